// Round 1
// baseline (4428.506 us; speedup 1.0000x reference)
//
#include <hip/hip_runtime.h>
#include <hip/hip_bf16.h>
#include <math.h>

#define B_ 2
#define S_ 1024
#define T_ (B_*S_)
#define D_ 2048
#define H_ 16
#define KV_ 4
#define DH_ 128
#define E_ 16
#define TOPK_ 2
#define I_ 1024
#define GROUPS_ (H_/KV_)
#define EPS_ 1e-6f

#define BM 128
#define BN 128
#define BK 16

#define BQ 32
#define TK 32

// ---------------- RMSNorm: one block per token row of D=2048 ----------------
__global__ __launch_bounds__(256) void rmsnorm_k(const float* __restrict__ x,
                                                 const float* __restrict__ w,
                                                 float* __restrict__ out) {
  int t = blockIdx.x;
  int tid = threadIdx.x;
  const float4* row = (const float4*)(x + (size_t)t * D_);
  float4 v0 = row[tid];
  float4 v1 = row[tid + 256];
  float ss = v0.x*v0.x + v0.y*v0.y + v0.z*v0.z + v0.w*v0.w
           + v1.x*v1.x + v1.y*v1.y + v1.z*v1.z + v1.w*v1.w;
#pragma unroll
  for (int o = 32; o > 0; o >>= 1) ss += __shfl_down(ss, o);
  __shared__ float sred[4];
  if ((tid & 63) == 0) sred[tid >> 6] = ss;
  __syncthreads();
  float tot = sred[0] + sred[1] + sred[2] + sred[3];
  float sc = rsqrtf(tot * (1.0f / D_) + EPS_);
  const float4* w4 = (const float4*)w;
  float4 wa = w4[tid], wb = w4[tid + 256];
  float4* o4 = (float4*)(out + (size_t)t * D_);
  float4 r0, r1;
  r0.x = v0.x * sc * wa.x; r0.y = v0.y * sc * wa.y;
  r0.z = v0.z * sc * wa.z; r0.w = v0.w * sc * wa.w;
  r1.x = v1.x * sc * wb.x; r1.y = v1.y * sc * wb.y;
  r1.z = v1.z * sc * wb.z; r1.w = v1.w * sc * wb.w;
  o4[tid] = r0;
  o4[tid + 256] = r1;
}

// ---------------- plain SGEMM C[M,N] = A[M,K]@B[K,N] (+addend) ----------------
__global__ __launch_bounds__(256) void sgemm_nn(const float* __restrict__ A,
                                                const float* __restrict__ B,
                                                float* __restrict__ C,
                                                const float* __restrict__ addend,
                                                int M, int N, int K) {
  __shared__ float As[BK][BM + 1];
  __shared__ float Bs[BK][BN];
  int tid = threadIdx.x;
  int tx = tid & 15, ty = tid >> 4;
  int m0 = blockIdx.y * BM, n0 = blockIdx.x * BN;
  float acc[8][8];
#pragma unroll
  for (int r = 0; r < 8; ++r)
#pragma unroll
    for (int c = 0; c < 8; ++c) acc[r][c] = 0.f;
  for (int k0 = 0; k0 < K; k0 += BK) {
#pragma unroll
    for (int i = 0; i < 8; ++i) {
      int el = tid + 256 * i;
      int m = el >> 4, kk = el & 15;
      As[kk][m] = A[(size_t)(m0 + m) * K + k0 + kk];
    }
#pragma unroll
    for (int i = 0; i < 8; ++i) {
      int el = tid + 256 * i;
      int kk = el >> 7, nn = el & 127;
      Bs[kk][nn] = B[(size_t)(k0 + kk) * N + n0 + nn];
    }
    __syncthreads();
#pragma unroll
    for (int kk = 0; kk < BK; ++kk) {
      float a[8], b[8];
#pragma unroll
      for (int r = 0; r < 8; ++r) a[r] = As[kk][ty * 8 + r];
#pragma unroll
      for (int c = 0; c < 8; ++c) b[c] = Bs[kk][tx * 8 + c];
#pragma unroll
      for (int r = 0; r < 8; ++r)
#pragma unroll
        for (int c = 0; c < 8; ++c) acc[r][c] += a[r] * b[c];
    }
    __syncthreads();
  }
#pragma unroll
  for (int r = 0; r < 8; ++r) {
    int m = m0 + ty * 8 + r;
#pragma unroll
    for (int c = 0; c < 8; ++c) {
      int n = n0 + tx * 8 + c;
      float vv = acc[r][c];
      if (addend) vv += addend[(size_t)m * N + n];
      C[(size_t)m * N + n] = vv;
    }
  }
}

// ---------------- expert SGEMM with row gather/scatter, per-expert B ----------------
__global__ __launch_bounds__(256) void sgemm_expert(
    const float* __restrict__ A, const int* __restrict__ a_gather,
    const float* __restrict__ Ball, size_t strideB, float* __restrict__ C,
    const int* __restrict__ c_scatter, const int* __restrict__ counts,
    const int* __restrict__ offsets, int N, int K) {
  int e = blockIdx.z;
  int cnt = counts[e];
  int m0 = blockIdx.y * BM;
  if (m0 >= cnt) return;
  int off = offsets[e];
  const float* Bp = Ball + (size_t)e * strideB;
  int n0 = blockIdx.x * BN;
  int tid = threadIdx.x;
  int tx = tid & 15, ty = tid >> 4;

  __shared__ float As[BK][BM + 1];
  __shared__ float Bs[BK][BN];
  __shared__ int rowIdx[BM];
  if (tid < BM) {
    int lm = m0 + tid;
    rowIdx[tid] = (lm < cnt) ? (a_gather ? a_gather[off + lm] : off + lm) : -1;
  }
  __syncthreads();
  float acc[8][8];
#pragma unroll
  for (int r = 0; r < 8; ++r)
#pragma unroll
    for (int c = 0; c < 8; ++c) acc[r][c] = 0.f;
  for (int k0 = 0; k0 < K; k0 += BK) {
#pragma unroll
    for (int i = 0; i < 8; ++i) {
      int el = tid + 256 * i;
      int m = el >> 4, kk = el & 15;
      int ra = rowIdx[m];
      As[kk][m] = (ra >= 0) ? A[(size_t)ra * K + k0 + kk] : 0.0f;
    }
#pragma unroll
    for (int i = 0; i < 8; ++i) {
      int el = tid + 256 * i;
      int kk = el >> 7, nn = el & 127;
      Bs[kk][nn] = Bp[(size_t)(k0 + kk) * N + n0 + nn];
    }
    __syncthreads();
#pragma unroll
    for (int kk = 0; kk < BK; ++kk) {
      float a[8], b[8];
#pragma unroll
      for (int r = 0; r < 8; ++r) a[r] = As[kk][ty * 8 + r];
#pragma unroll
      for (int c = 0; c < 8; ++c) b[c] = Bs[kk][tx * 8 + c];
#pragma unroll
      for (int r = 0; r < 8; ++r)
#pragma unroll
        for (int c = 0; c < 8; ++c) acc[r][c] += a[r] * b[c];
    }
    __syncthreads();
  }
#pragma unroll
  for (int r = 0; r < 8; ++r) {
    int lm = m0 + ty * 8 + r;
    if (lm >= cnt) continue;
    int crow = c_scatter ? c_scatter[off + lm] : off + lm;
    float* Crow = C + (size_t)crow * N + n0 + tx * 8;
#pragma unroll
    for (int c = 0; c < 8; ++c) Crow[c] = acc[r][c];
  }
}

// ---------------- per-head QK RMSNorm + RoPE (in place) ----------------
__global__ __launch_bounds__(128) void qknorm_rope_k(
    float* __restrict__ q, float* __restrict__ k,
    const float* __restrict__ qn_w, const float* __restrict__ kn_w,
    const int* __restrict__ pos_ids) {
  int t = blockIdx.x;
  int head = blockIdx.y;
  int d = threadIdx.x;
  float* base;
  const float* w;
  if (head < H_) {
    base = q + ((size_t)t * H_ + head) * DH_;
    w = qn_w;
  } else {
    base = k + ((size_t)t * KV_ + (head - H_)) * DH_;
    w = kn_w;
  }
  float val = base[d];
  float ss = val * val;
#pragma unroll
  for (int o = 32; o > 0; o >>= 1) ss += __shfl_down(ss, o);
  __shared__ float sred[2];
  __shared__ float vnorm[DH_];
  if ((d & 63) == 0) sred[d >> 6] = ss;
  __syncthreads();
  float tot = sred[0] + sred[1];
  float sc = rsqrtf(tot * (1.0f / DH_) + EPS_);
  float nv = val * sc * w[d];
  vnorm[d] = nv;
  __syncthreads();
  float pos = (float)pos_ids[t];
  int pi = d & 63;
  // inv_freq = THETA^(-2*pi/128), THETA=1e6 ; log(1e6)=13.815510558
  float inv = expf(-(2.0f * (float)pi) * (1.0f / 128.0f) * 13.815510558f);
  float ang = pos * inv;
  float c = cosf(ang), s = sinf(ang);
  float partner = (d < 64) ? -vnorm[d + 64] : vnorm[d - 64];
  base[d] = nv * c + partner * s;
}

// ---------------- flash-style causal GQA attention ----------------
__global__ __launch_bounds__(256) void attn_k(const float* __restrict__ q,
                                              const float* __restrict__ k,
                                              const float* __restrict__ v,
                                              float* __restrict__ o) {
  const int qt = blockIdx.x;
  const int bh = blockIdx.y;
  const int b = bh / H_, h = bh % H_;
  const int kvh = h / GROUPS_;
  const int tid = threadIdx.x;
  const int r = tid >> 3;
  const int jb = (tid & 7) * 4;
  const int d0 = (tid & 7) * 16;

  __shared__ float Qs[BQ][DH_];
  __shared__ float Ks[TK][DH_];
  __shared__ float Vs[TK][DH_];
  __shared__ float Ss[BQ][TK];

#pragma unroll
  for (int i = 0; i < 4; ++i) {
    int el = tid + 256 * i;
    int row = el >> 5, c4 = el & 31;
    int t = b * S_ + qt * BQ + row;
    ((float4*)&Qs[row][0])[c4] =
        ((const float4*)(q + ((size_t)t * H_ + h) * DH_))[c4];
  }

  float acc[16];
#pragma unroll
  for (int i = 0; i < 16; ++i) acc[i] = 0.f;
  float m_run = -1e30f, l_run = 0.f;
  const float scale = 0.08838834764831845f;  // 1/sqrt(128)

  for (int jt = 0; jt <= qt; ++jt) {
    __syncthreads();  // staging hazard barrier (also covers Q stage on iter 0)
#pragma unroll
    for (int i = 0; i < 4; ++i) {
      int el = tid + 256 * i;
      int row = el >> 5, c4 = el & 31;
      int t = b * S_ + jt * TK + row;
      const float4* kb = (const float4*)(k + ((size_t)t * KV_ + kvh) * DH_);
      const float4* vb = (const float4*)(v + ((size_t)t * KV_ + kvh) * DH_);
      ((float4*)&Ks[row][0])[c4] = kb[c4];
      ((float4*)&Vs[row][0])[c4] = vb[c4];
    }
    __syncthreads();
    // scores: 4 per thread
    float sv[4] = {0.f, 0.f, 0.f, 0.f};
    const float4* qrow = (const float4*)&Qs[r][0];
#pragma unroll 8
    for (int dd = 0; dd < 32; ++dd) {
      int d4 = (dd + (tid & 7) * 4) & 31;  // stagger to spread LDS banks
      float4 qv = qrow[d4];
#pragma unroll
      for (int jj = 0; jj < 4; ++jj) {
        float4 kv4 = ((const float4*)&Ks[jb + jj][0])[d4];
        sv[jj] += qv.x * kv4.x + qv.y * kv4.y + qv.z * kv4.z + qv.w * kv4.w;
      }
    }
    int qg = qt * BQ + r;
    float tmax = -1e30f;
#pragma unroll
    for (int jj = 0; jj < 4; ++jj) {
      int jg = jt * TK + jb + jj;
      sv[jj] = (jg <= qg) ? sv[jj] * scale : -1e30f;
      tmax = fmaxf(tmax, sv[jj]);
    }
#pragma unroll
    for (int msk = 1; msk < 8; msk <<= 1)
      tmax = fmaxf(tmax, __shfl_xor(tmax, msk));
    float mnew = fmaxf(m_run, tmax);
    float f = expf(m_run - mnew);
    float psum = 0.f;
#pragma unroll
    for (int jj = 0; jj < 4; ++jj) {
      float p = expf(sv[jj] - mnew);
      Ss[r][jb + jj] = p;
      psum += p;
    }
#pragma unroll
    for (int msk = 1; msk < 8; msk <<= 1) psum += __shfl_xor(psum, msk);
    l_run = l_run * f + psum;
    m_run = mnew;
#pragma unroll
    for (int i = 0; i < 16; ++i) acc[i] *= f;
    __syncthreads();
    // PV
#pragma unroll 4
    for (int j = 0; j < TK; ++j) {
      float pj = Ss[r][j];
      const float4* vrow = (const float4*)&Vs[j][0];
#pragma unroll
      for (int dd = 0; dd < 4; ++dd) {
        float4 vv = vrow[(d0 >> 2) + dd];
        acc[dd * 4 + 0] += pj * vv.x;
        acc[dd * 4 + 1] += pj * vv.y;
        acc[dd * 4 + 2] += pj * vv.z;
        acc[dd * 4 + 3] += pj * vv.w;
      }
    }
  }
  float invl = 1.0f / l_run;
  int t = b * S_ + qt * BQ + r;
  float* ob = o + ((size_t)t * H_ + h) * DH_ + d0;
#pragma unroll
  for (int dd = 0; dd < 4; ++dd) {
    float4 res;
    res.x = acc[dd * 4 + 0] * invl;
    res.y = acc[dd * 4 + 1] * invl;
    res.z = acc[dd * 4 + 2] * invl;
    res.w = acc[dd * 4 + 3] * invl;
    ((float4*)ob)[dd] = res;
  }
}

// ---------------- router: logits, softmax, top-2, counts ----------------
__global__ __launch_bounds__(256) void router_k(const float* __restrict__ h2,
                                                const float* __restrict__ rw,
                                                float* __restrict__ topv,
                                                int* __restrict__ topi,
                                                int* __restrict__ counts) {
  int t = blockIdx.x;
  int tid = threadIdx.x;
  const float* row = h2 + (size_t)t * D_;
  float acc[E_];
#pragma unroll
  for (int e2 = 0; e2 < E_; ++e2) acc[e2] = 0.f;
  for (int d = tid; d < D_; d += 256) {
    float xv = row[d];
    const float4* rr = (const float4*)(rw + (size_t)d * E_);
#pragma unroll
    for (int e4 = 0; e4 < 4; ++e4) {
      float4 wv = rr[e4];
      acc[e4 * 4 + 0] += xv * wv.x;
      acc[e4 * 4 + 1] += xv * wv.y;
      acc[e4 * 4 + 2] += xv * wv.z;
      acc[e4 * 4 + 3] += xv * wv.w;
    }
  }
  __shared__ float red[256][E_];
#pragma unroll
  for (int e2 = 0; e2 < E_; ++e2) red[tid][e2] = acc[e2];
  __syncthreads();
  __shared__ float wlog[E_];
  if (tid < E_) {
    float s = 0.f;
    for (int i = 0; i < 256; ++i) s += red[i][tid];
    wlog[tid] = s;
  }
  __syncthreads();
  if (tid == 0) {
    float mx = wlog[0];
    for (int e2 = 1; e2 < E_; ++e2) mx = fmaxf(mx, wlog[e2]);
    float pe[E_];
    float se = 0.f;
    for (int e2 = 0; e2 < E_; ++e2) {
      pe[e2] = expf(wlog[e2] - mx);
      se += pe[e2];
    }
    float invs = 1.f / se;
    for (int e2 = 0; e2 < E_; ++e2) pe[e2] *= invs;
    int i0 = 0;
    float p0 = pe[0];
    for (int e2 = 1; e2 < E_; ++e2)
      if (pe[e2] > p0) { p0 = pe[e2]; i0 = e2; }
    int i1 = -1;
    float p1 = -1.f;
    for (int e2 = 0; e2 < E_; ++e2) {
      if (e2 == i0) continue;
      if (pe[e2] > p1) { p1 = pe[e2]; i1 = e2; }
    }
    float wsum = p0 + p1;
    topi[2 * t] = i0;
    topi[2 * t + 1] = i1;
    topv[2 * t] = p0 / wsum;
    topv[2 * t + 1] = p1 / wsum;
    atomicAdd(&counts[i0], 1);
    atomicAdd(&counts[i1], 1);
  }
}

__global__ void zero_k(int* __restrict__ counts) {
  if (threadIdx.x < E_) counts[threadIdx.x] = 0;
}

__global__ void offsets_k(const int* __restrict__ counts, int* __restrict__ offs,
                          int* __restrict__ cursor) {
  if (threadIdx.x == 0) {
    int s = 0;
    for (int e2 = 0; e2 < E_; ++e2) {
      offs[e2] = s;
      s += counts[e2];
    }
    offs[E_] = s;
  }
  if (threadIdx.x < E_) cursor[threadIdx.x] = 0;
}

__global__ __launch_bounds__(256) void pairs_k(
    const int* __restrict__ topi, const float* __restrict__ topv,
    const int* __restrict__ offs, int* __restrict__ cursor,
    int* __restrict__ pair_token, float* __restrict__ pair_w,
    int* __restrict__ pair_slot) {
  int t = blockIdx.x * blockDim.x + threadIdx.x;
  if (t >= T_) return;
#pragma unroll
  for (int kk = 0; kk < TOPK_; ++kk) {
    int e2 = topi[2 * t + kk];
    int p = offs[e2] + atomicAdd(&cursor[e2], 1);
    pair_token[p] = t;
    pair_w[p] = topv[2 * t + kk];
    pair_slot[p] = 2 * t + kk;
  }
}

// act = silu(g)*u*w ; in-place into bufG
__global__ __launch_bounds__(256) void act_k(float* __restrict__ bufG,
                                             const float* __restrict__ bufU,
                                             const float* __restrict__ pair_w) {
  int idx = blockIdx.x * blockDim.x + threadIdx.x;
  int stride = gridDim.x * blockDim.x;
  int n4 = T_ * TOPK_ * I_ / 4;
  float4* G4 = (float4*)bufG;
  const float4* U4 = (const float4*)bufU;
  for (; idx < n4; idx += stride) {
    int p = idx >> 8;  // I_/4 = 256 float4 per row
    float w = pair_w[p];
    float4 g = G4[idx], u = U4[idx];
    float4 res;
    res.x = (g.x / (1.f + expf(-g.x))) * u.x * w;
    res.y = (g.y / (1.f + expf(-g.y))) * u.y * w;
    res.z = (g.z / (1.f + expf(-g.z))) * u.z * w;
    res.w = (g.w / (1.f + expf(-g.w))) * u.w * w;
    G4[idx] = res;
  }
}

__global__ __launch_bounds__(256) void final_k(const float* __restrict__ x2,
                                               const float* __restrict__ slots,
                                               float* __restrict__ out) {
  int idx = blockIdx.x * blockDim.x + threadIdx.x;
  int stride = gridDim.x * blockDim.x;
  int n4 = T_ * D_ / 4;
  const int rowq = D_ / 4;  // 512
  const float4* X4 = (const float4*)x2;
  const float4* S4 = (const float4*)slots;
  float4* O4 = (float4*)out;
  for (; idx < n4; idx += stride) {
    int t = idx / rowq;
    int d4 = idx % rowq;
    float4 a = X4[idx];
    float4 s0 = S4[(size_t)(2 * t) * rowq + d4];
    float4 s1 = S4[(size_t)(2 * t + 1) * rowq + d4];
    float4 res;
    res.x = a.x + s0.x + s1.x;
    res.y = a.y + s0.y + s1.y;
    res.z = a.z + s0.z + s1.z;
    res.w = a.w + s0.w + s1.w;
    O4[idx] = res;
  }
}

extern "C" void kernel_launch(void* const* d_in, const int* in_sizes, int n_in,
                              void* d_out, int out_size, void* d_ws, size_t ws_size,
                              hipStream_t stream) {
  const float* x = (const float*)d_in[0];
  const int* pos = (const int*)d_in[1];
  const float* ln1_w = (const float*)d_in[2];
  const float* q_w = (const float*)d_in[3];
  const float* k_w = (const float*)d_in[4];
  const float* v_w = (const float*)d_in[5];
  const float* o_w = (const float*)d_in[6];
  const float* qn_w = (const float*)d_in[7];
  const float* kn_w = (const float*)d_in[8];
  const float* ln2_w = (const float*)d_in[9];
  const float* router_w = (const float*)d_in[10];
  const float* gate_w = (const float*)d_in[11];
  const float* up_w = (const float*)d_in[12];
  const float* down_w = (const float*)d_in[13];
  float* out = (float*)d_out;

  float* wsf = (float*)d_ws;
  size_t off = 0;
  float* hbuf = wsf + off; off += (size_t)T_ * D_;        // rms1 out, reused as h2
  float* qbuf = wsf + off; off += (size_t)T_ * H_ * DH_;
  float* kbuf = wsf + off; off += (size_t)T_ * KV_ * DH_;
  float* vbuf = wsf + off; off += (size_t)T_ * KV_ * DH_;
  float* attnb = wsf + off; off += (size_t)T_ * H_ * DH_;
  float* x2 = wsf + off; off += (size_t)T_ * D_;
  float* bufG = wsf + off; off += (size_t)T_ * TOPK_ * I_;
  float* bufU = wsf + off; off += (size_t)T_ * TOPK_ * I_;
  float* slots = wsf + off; off += (size_t)T_ * TOPK_ * D_;
  float* topv = wsf + off; off += T_ * TOPK_;
  float* pair_w = wsf + off; off += T_ * TOPK_;
  int* ib = (int*)(wsf + off);
  int* topi = ib; ib += T_ * TOPK_;
  int* counts = ib; ib += E_;
  int* offs = ib; ib += E_ + 1;
  int* cursor = ib; ib += E_;
  int* pair_token = ib; ib += T_ * TOPK_;
  int* pair_slot = ib; ib += T_ * TOPK_;

  // ---- attention block ----
  rmsnorm_k<<<T_, 256, 0, stream>>>(x, ln1_w, hbuf);
  sgemm_nn<<<dim3((H_ * DH_) / BN, T_ / BM), 256, 0, stream>>>(
      hbuf, q_w, qbuf, nullptr, T_, H_ * DH_, D_);
  sgemm_nn<<<dim3((KV_ * DH_) / BN, T_ / BM), 256, 0, stream>>>(
      hbuf, k_w, kbuf, nullptr, T_, KV_ * DH_, D_);
  sgemm_nn<<<dim3((KV_ * DH_) / BN, T_ / BM), 256, 0, stream>>>(
      hbuf, v_w, vbuf, nullptr, T_, KV_ * DH_, D_);
  qknorm_rope_k<<<dim3(T_, H_ + KV_), 128, 0, stream>>>(qbuf, kbuf, qn_w, kn_w, pos);
  attn_k<<<dim3(S_ / BQ, B_ * H_), 256, 0, stream>>>(qbuf, kbuf, vbuf, attnb);
  sgemm_nn<<<dim3(D_ / BN, T_ / BM), 256, 0, stream>>>(
      attnb, o_w, x2, x, T_, D_, H_ * DH_);

  // ---- MoE block ----
  rmsnorm_k<<<T_, 256, 0, stream>>>(x2, ln2_w, hbuf);  // h2
  zero_k<<<1, 64, 0, stream>>>(counts);
  router_k<<<T_, 256, 0, stream>>>(hbuf, router_w, topv, topi, counts);
  offsets_k<<<1, 64, 0, stream>>>(counts, offs, cursor);
  pairs_k<<<T_ / 256, 256, 0, stream>>>(topi, topv, offs, cursor, pair_token,
                                        pair_w, pair_slot);
  sgemm_expert<<<dim3(I_ / BN, 16, E_), 256, 0, stream>>>(
      hbuf, pair_token, gate_w, (size_t)D_ * I_, bufG, nullptr, counts, offs,
      I_, D_);
  sgemm_expert<<<dim3(I_ / BN, 16, E_), 256, 0, stream>>>(
      hbuf, pair_token, up_w, (size_t)D_ * I_, bufU, nullptr, counts, offs,
      I_, D_);
  act_k<<<2048, 256, 0, stream>>>(bufG, bufU, pair_w);
  sgemm_expert<<<dim3(D_ / BN, 16, E_), 256, 0, stream>>>(
      bufG, nullptr, down_w, (size_t)I_ * D_, slots, pair_slot, counts, offs,
      D_, I_);
  final_k<<<2048, 256, 0, stream>>>(x2, slots, out);
}

// Round 3
// 1171.728 us; speedup vs baseline: 3.7795x; 3.7795x over previous
//
#include <hip/hip_runtime.h>
#include <hip/hip_bf16.h>
#include <math.h>

#define B_ 2
#define S_ 1024
#define T_ (B_*S_)
#define D_ 2048
#define H_ 16
#define KV_ 4
#define DH_ 128
#define E_ 16
#define TOPK_ 2
#define I_ 1024
#define GROUPS_ (H_/KV_)
#define EPS_ 1e-6f
#define QKVN_ 3072

typedef __attribute__((ext_vector_type(8))) short short8;
typedef __attribute__((ext_vector_type(4))) float f32x4;
typedef unsigned int uint;

__device__ __forceinline__ ushort f2bf(float f) {
  union { float f; uint u; } v; v.f = f;
  uint r = v.u + 0x7fffu + ((v.u >> 16) & 1u);
  return (ushort)(r >> 16);
}
__device__ __forceinline__ float bf2f(ushort h) {
  union { uint u; float f; } v; v.u = ((uint)h) << 16;
  return v.f;
}
__device__ __forceinline__ uint pack2(float a, float b) {
  return (uint)f2bf(a) | ((uint)f2bf(b) << 16);
}
// split a into hi+lo bf16
__device__ __forceinline__ void split1(float a, ushort& hi, ushort& lo) {
  hi = f2bf(a);
  lo = f2bf(a - bf2f(hi));
}
__device__ __forceinline__ void pack2_split(float a, float b, uint& h, uint& l) {
  ushort ah, al, bh, bl;
  split1(a, ah, al);
  split1(b, bh, bl);
  h = (uint)ah | ((uint)bh << 16);
  l = (uint)al | ((uint)bl << 16);
}

// ---------------- RMSNorm fp32 -> split bf16 hi/lo ----------------
__global__ __launch_bounds__(256) void rmsnorm_split_k(const float* __restrict__ x,
                                                       const float* __restrict__ w,
                                                       ushort* __restrict__ hi,
                                                       ushort* __restrict__ lo) {
  int t = blockIdx.x;
  int tid = threadIdx.x;
  const float4* row = (const float4*)(x + (size_t)t * D_);
  float4 v0 = row[tid * 2], v1 = row[tid * 2 + 1];
  float ss = v0.x*v0.x + v0.y*v0.y + v0.z*v0.z + v0.w*v0.w
           + v1.x*v1.x + v1.y*v1.y + v1.z*v1.z + v1.w*v1.w;
#pragma unroll
  for (int o = 32; o > 0; o >>= 1) ss += __shfl_down(ss, o);
  __shared__ float sred[4];
  if ((tid & 63) == 0) sred[tid >> 6] = ss;
  __syncthreads();
  float tot = sred[0] + sred[1] + sred[2] + sred[3];
  float sc = rsqrtf(tot * (1.0f / D_) + EPS_);
  const float4* w4 = (const float4*)w;
  float4 wa = w4[tid * 2], wb = w4[tid * 2 + 1];
  uint4 oh, ol;
  pack2_split(v0.x * sc * wa.x, v0.y * sc * wa.y, oh.x, ol.x);
  pack2_split(v0.z * sc * wa.z, v0.w * sc * wa.w, oh.y, ol.y);
  pack2_split(v1.x * sc * wb.x, v1.y * sc * wb.y, oh.z, ol.z);
  pack2_split(v1.z * sc * wb.z, v1.w * sc * wb.w, oh.w, ol.w);
  ((uint4*)(hi + (size_t)t * D_))[tid] = oh;
  ((uint4*)(lo + (size_t)t * D_))[tid] = ol;
}

// ---------------- RMSNorm fp32 -> plain bf16 (expert input) ----------------
__global__ __launch_bounds__(256) void rmsnorm_bf16_k(const float* __restrict__ x,
                                                      const float* __restrict__ w,
                                                      ushort* __restrict__ out) {
  int t = blockIdx.x;
  int tid = threadIdx.x;
  const float4* row = (const float4*)(x + (size_t)t * D_);
  float4 v0 = row[tid * 2], v1 = row[tid * 2 + 1];
  float ss = v0.x*v0.x + v0.y*v0.y + v0.z*v0.z + v0.w*v0.w
           + v1.x*v1.x + v1.y*v1.y + v1.z*v1.z + v1.w*v1.w;
#pragma unroll
  for (int o = 32; o > 0; o >>= 1) ss += __shfl_down(ss, o);
  __shared__ float sred[4];
  if ((tid & 63) == 0) sred[tid >> 6] = ss;
  __syncthreads();
  float tot = sred[0] + sred[1] + sred[2] + sred[3];
  float sc = rsqrtf(tot * (1.0f / D_) + EPS_);
  const float4* w4 = (const float4*)w;
  float4 wa = w4[tid * 2], wb = w4[tid * 2 + 1];
  uint4 o4;
  o4.x = pack2(v0.x * sc * wa.x, v0.y * sc * wa.y);
  o4.y = pack2(v0.z * sc * wa.z, v0.w * sc * wa.w);
  o4.z = pack2(v1.x * sc * wb.x, v1.y * sc * wb.y);
  o4.w = pack2(v1.z * sc * wb.z, v1.w * sc * wb.w);
  ((uint4*)(out + (size_t)t * D_))[tid] = o4;
}

// ---------------- weight transpose + split: W[K][N] -> Wt hi/lo [row_off+n][k] ----------------
__global__ __launch_bounds__(256) void transpose_split_k(
    const float* __restrict__ src, ushort* __restrict__ dhi,
    ushort* __restrict__ dlo, int N, int row_off, int dst_ld) {
  __shared__ float tbuf[32][33];
  int n0 = blockIdx.x * 32, k0 = blockIdx.y * 32;
  int tx = threadIdx.x & 31, ty = threadIdx.x >> 5;
#pragma unroll
  for (int j = 0; j < 4; ++j)
    tbuf[ty + j * 8][tx] = src[(size_t)(k0 + ty + j * 8) * N + n0 + tx];
  __syncthreads();
#pragma unroll
  for (int j = 0; j < 2; ++j) {
    int idx = threadIdx.x + j * 256;
    int n = idx >> 4;
    int kq = (idx & 15) * 2;
    uint ph, pl;
    pack2_split(tbuf[kq][n], tbuf[kq + 1][n], ph, pl);
    size_t o = (size_t)(row_off + n0 + n) * dst_ld + k0 + kq;
    *(uint*)(dhi + o) = ph;
    *(uint*)(dlo + o) = pl;
  }
}

// ---------------- split-bf16 3-pass MFMA GEMM: C = A@B^T (+addend) ----------------
__global__ __launch_bounds__(256) void gemm_split_k(
    const ushort* __restrict__ Ahi, const ushort* __restrict__ Alo,
    const ushort* __restrict__ Bhi, const ushort* __restrict__ Blo,
    float* __restrict__ C, const float* __restrict__ addend,
    int M, int N, int K) {
  int m0 = blockIdx.y * 128, n0 = blockIdx.x * 128;
  __shared__ ushort AsH[128 * 64], AsL[128 * 64];
  __shared__ ushort BsH[128 * 64], BsL[128 * 64];
  int tid = threadIdx.x;
  int row_s = tid >> 1, kh = tid & 1;
  const size_t aoff = (size_t)(m0 + row_s) * K;
  const size_t boff = (size_t)(n0 + row_s) * K;
  int wid = tid >> 6, lane = tid & 63;
  int wr = wid >> 1, wc = wid & 1;
  int lr = lane & 15, lk = lane >> 4;

  f32x4 acc[4][4];
#pragma unroll
  for (int m = 0; m < 4; ++m)
#pragma unroll
    for (int n = 0; n < 4; ++n) acc[m][n] = (f32x4){0.f, 0.f, 0.f, 0.f};

  const int nt = K >> 6;
  for (int t = 0; t < nt; ++t) {
    int k0g = t << 6;
    __syncthreads();
    uint4 r0[4], r1[4], r2[4], r3[4];
#pragma unroll
    for (int c = 0; c < 4; ++c) {
      int k = k0g + kh * 32 + c * 8;
      r0[c] = *(const uint4*)(Ahi + aoff + k);
      r1[c] = *(const uint4*)(Alo + aoff + k);
      r2[c] = *(const uint4*)(Bhi + boff + k);
      r3[c] = *(const uint4*)(Blo + boff + k);
    }
#pragma unroll
    for (int c = 0; c < 4; ++c) {
      int addr = row_s * 128 + (((kh * 4 + c) * 16) ^ ((row_s & 7) << 4));
      *(uint4*)((char*)AsH + addr) = r0[c];
      *(uint4*)((char*)AsL + addr) = r1[c];
      *(uint4*)((char*)BsH + addr) = r2[c];
      *(uint4*)((char*)BsL + addr) = r3[c];
    }
    __syncthreads();
#pragma unroll
    for (int kk = 0; kk < 2; ++kk) {
      short8 ah[4], al[4], bh[4], bl[4];
      int kbyte = kk * 64 + lk * 16;
#pragma unroll
      for (int m = 0; m < 4; ++m) {
        int row = wr * 64 + m * 16 + lr;
        int ad = row * 128 + (kbyte ^ ((row & 7) << 4));
        ah[m] = *(const short8*)((const char*)AsH + ad);
        al[m] = *(const short8*)((const char*)AsL + ad);
      }
#pragma unroll
      for (int n = 0; n < 4; ++n) {
        int row = wc * 64 + n * 16 + lr;
        int ad = row * 128 + (kbyte ^ ((row & 7) << 4));
        bh[n] = *(const short8*)((const char*)BsH + ad);
        bl[n] = *(const short8*)((const char*)BsL + ad);
      }
#pragma unroll
      for (int m = 0; m < 4; ++m)
#pragma unroll
        for (int n = 0; n < 4; ++n) {
          acc[m][n] = __builtin_amdgcn_mfma_f32_16x16x32_bf16(ah[m], bh[n], acc[m][n], 0, 0, 0);
          acc[m][n] = __builtin_amdgcn_mfma_f32_16x16x32_bf16(al[m], bh[n], acc[m][n], 0, 0, 0);
          acc[m][n] = __builtin_amdgcn_mfma_f32_16x16x32_bf16(ah[m], bl[n], acc[m][n], 0, 0, 0);
        }
    }
  }
#pragma unroll
  for (int m = 0; m < 4; ++m) {
    int lrow = wr * 64 + m * 16 + (lane >> 4) * 4;
#pragma unroll
    for (int j = 0; j < 4; ++j) {
      int crow = m0 + lrow + j;
      float* Crow = C + (size_t)crow * N;
#pragma unroll
      for (int n = 0; n < 4; ++n) {
        int col = n0 + wc * 64 + n * 16 + lr;
        float vv = acc[m][n][j];
        if (addend) vv += addend[(size_t)crow * N + col];
        Crow[col] = vv;
      }
    }
  }
}

// ---------------- plain bf16 MFMA GEMM for expert path ----------------
// MODE 1: gathered A rows (pair_token), B = gate/up fp32 [K][1024] per expert
// MODE 2: A rows = pair index, B = down fp32 [K][N] per expert, C rows scattered
template <int MODE>
__global__ __launch_bounds__(256) void gemm_k(
    const ushort* __restrict__ A, const float* __restrict__ Wf0,
    const float* __restrict__ Wf1, float* __restrict__ C,
    const int* __restrict__ gather, const int* __restrict__ scatter,
    const int* __restrict__ counts, const int* __restrict__ offsets,
    int N, int K) {
  int e = blockIdx.z;
  int cnt = counts[e];
  int m0 = blockIdx.y * 128;
  if (m0 >= cnt) return;
  int off = offsets[e];
  int n0 = blockIdx.x * 128;

  __shared__ ushort As[128 * 64];
  __shared__ ushort Bs[128 * 64];
  __shared__ int rowIdx[128];

  int tid = threadIdx.x;
  if (tid < 128) {
    int lm = m0 + tid;
    rowIdx[tid] = (lm < cnt) ? (gather ? gather[off + lm] : off + lm) : -1;
  }
  __syncthreads();

  const float* Wsel;
  int ldw, nb;
  if (MODE == 1) {
    ldw = 1024;
    Wsel = ((n0 < 1024) ? Wf0 : Wf1) + (size_t)e * (size_t)K * 1024;
    nb = n0 & 1023;
  } else {
    ldw = N;
    Wsel = Wf0 + (size_t)e * (size_t)K * (size_t)N;
    nb = n0;
  }

  const int row_s = tid >> 1;
  const int kh = tid & 1;
  const int arow = rowIdx[row_s];

  uint4 ra[4];
  uint4 rbv[4];
  uint* rb = (uint*)rbv;

  auto loadA = [&](int k0g) {
#pragma unroll
    for (int c = 0; c < 4; ++c) {
      int k = k0g + kh * 32 + c * 8;
      if (arow >= 0)
        ra[c] = *(const uint4*)(A + (size_t)arow * K + k);
      else
        ra[c] = make_uint4(0u, 0u, 0u, 0u);
    }
  };
  auto loadB = [&](int k0g) {
    int col = nb + (tid & 127);
    int kbase = k0g + (tid >> 7) * 32;
    const float* p = Wsel + (size_t)kbase * ldw + col;
#pragma unroll
    for (int i = 0; i < 16; ++i) {
      float f0 = p[(size_t)(2 * i) * ldw];
      float f1 = p[(size_t)(2 * i + 1) * ldw];
      rb[i] = pack2(f0, f1);
    }
  };
  auto writeLDS = [&]() {
    char* Ab = (char*)As;
#pragma unroll
    for (int c = 0; c < 4; ++c) {
      int kbyte = (kh * 4 + c) * 16;
      int addr = row_s * 128 + (kbyte ^ ((row_s & 7) << 4));
      *(uint4*)(Ab + addr) = ra[c];
    }
    char* Bb = (char*)Bs;
    int n_l = tid & 127;
    int khb = tid >> 7;
#pragma unroll
    for (int c = 0; c < 4; ++c) {
      int kbyte = (khb * 4 + c) * 16;
      int addr = n_l * 128 + (kbyte ^ ((n_l & 7) << 4));
      *(uint4*)(Bb + addr) = rbv[c];
    }
  };

  int wid = tid >> 6, lane = tid & 63;
  int wr = wid >> 1, wc = wid & 1;
  int lr = lane & 15, lk = lane >> 4;

  f32x4 acc[4][4];
#pragma unroll
  for (int m = 0; m < 4; ++m)
#pragma unroll
    for (int n = 0; n < 4; ++n) acc[m][n] = (f32x4){0.f, 0.f, 0.f, 0.f};

  const char* Ab = (const char*)As;
  const char* Bb = (const char*)Bs;

  int nt = K >> 6;
  loadA(0);
  loadB(0);
  for (int t = 0; t < nt; ++t) {
    __syncthreads();
    writeLDS();
    __syncthreads();
    if (t + 1 < nt) {
      loadA((t + 1) << 6);
      loadB((t + 1) << 6);
    }
#pragma unroll
    for (int kk = 0; kk < 2; ++kk) {
      short8 af[4], bfv[4];
#pragma unroll
      for (int m = 0; m < 4; ++m) {
        int row = wr * 64 + m * 16 + lr;
        int kbyte = kk * 64 + lk * 16;
        af[m] = *(const short8*)(Ab + row * 128 + (kbyte ^ ((row & 7) << 4)));
      }
#pragma unroll
      for (int n = 0; n < 4; ++n) {
        int row = wc * 64 + n * 16 + lr;
        int kbyte = kk * 64 + lk * 16;
        bfv[n] = *(const short8*)(Bb + row * 128 + (kbyte ^ ((row & 7) << 4)));
      }
#pragma unroll
      for (int m = 0; m < 4; ++m)
#pragma unroll
        for (int n = 0; n < 4; ++n)
          acc[m][n] = __builtin_amdgcn_mfma_f32_16x16x32_bf16(af[m], bfv[n],
                                                              acc[m][n], 0, 0, 0);
    }
  }

#pragma unroll
  for (int m = 0; m < 4; ++m) {
    int lrow = wr * 64 + m * 16 + (lane >> 4) * 4;
#pragma unroll
    for (int j = 0; j < 4; ++j) {
      int lm = lrow + j;
      if (m0 + lm >= cnt) continue;
      int crow;
      if (MODE == 2) crow = scatter[off + m0 + lm];
      else crow = off + m0 + lm;
      float* Crow = C + (size_t)crow * N;
#pragma unroll
      for (int n = 0; n < 4; ++n) {
        int col = n0 + wc * 64 + n * 16 + lr;
        Crow[col] = acc[m][n][j];
      }
    }
  }
}

// ---------------- per-head QK RMSNorm + RoPE on fused qkv (in place) ----------------
__global__ __launch_bounds__(128) void qknorm_rope_k(
    float* __restrict__ qkv, const float* __restrict__ qn_w,
    const float* __restrict__ kn_w, const int* __restrict__ pos_ids) {
  int t = blockIdx.x;
  int head = blockIdx.y;  // 0..15 q, 16..19 k
  int d = threadIdx.x;
  float* base;
  const float* w;
  if (head < H_) {
    base = qkv + (size_t)t * QKVN_ + head * DH_;
    w = qn_w;
  } else {
    base = qkv + (size_t)t * QKVN_ + 2048 + (head - H_) * DH_;
    w = kn_w;
  }
  float val = base[d];
  float ss = val * val;
#pragma unroll
  for (int o = 32; o > 0; o >>= 1) ss += __shfl_down(ss, o);
  __shared__ float sred[2];
  __shared__ float vnorm[DH_];
  if ((d & 63) == 0) sred[d >> 6] = ss;
  __syncthreads();
  float tot = sred[0] + sred[1];
  float sc = rsqrtf(tot * (1.0f / DH_) + EPS_);
  float nv = val * sc * w[d];
  vnorm[d] = nv;
  __syncthreads();
  float pos = (float)pos_ids[t];
  int pi = d & 63;
  float inv = expf(-(2.0f * (float)pi) * (1.0f / 128.0f) * 13.815510558f);
  float ang = pos * inv;
  float c = cosf(ang), s = sinf(ang);
  float partner = (d < 64) ? -vnorm[d + 64] : vnorm[d - 64];
  base[d] = nv * c + partner * s;
}

// ---------------- flash-style causal GQA attention (fp32, split bf16 out) ----------------
__global__ __launch_bounds__(256) void attn_k(const float* __restrict__ qkv,
                                              ushort* __restrict__ ohi,
                                              ushort* __restrict__ olo) {
  const int qt = blockIdx.x;
  const int bh = blockIdx.y;
  const int b = bh >> 4, h = bh & 15;
  const int kvh = h >> 2;
  const int tid = threadIdx.x;
  const int r = tid >> 3;
  const int jb = (tid & 7) * 4;
  const int d0 = (tid & 7) * 16;

  __shared__ float Qs[32][DH_];
  __shared__ float Ks[32][DH_];
  __shared__ float Vs[32][DH_];
  __shared__ float Ss[32][32];

#pragma unroll
  for (int i = 0; i < 4; ++i) {
    int el = tid + 256 * i;
    int row = el >> 5, c4 = el & 31;
    int t = b * S_ + qt * 32 + row;
    ((float4*)&Qs[row][0])[c4] =
        ((const float4*)(qkv + (size_t)t * QKVN_ + h * DH_))[c4];
  }

  float acc[16];
#pragma unroll
  for (int i = 0; i < 16; ++i) acc[i] = 0.f;
  float m_run = -1e30f, l_run = 0.f;
  const float scale = 0.08838834764831845f;

  for (int jt = 0; jt <= qt; ++jt) {
    __syncthreads();
#pragma unroll
    for (int i = 0; i < 4; ++i) {
      int el = tid + 256 * i;
      int row = el >> 5, c4 = el & 31;
      int t = b * S_ + jt * 32 + row;
      const float4* kb = (const float4*)(qkv + (size_t)t * QKVN_ + 2048 + kvh * DH_);
      const float4* vb = (const float4*)(qkv + (size_t)t * QKVN_ + 2560 + kvh * DH_);
      ((float4*)&Ks[row][0])[c4] = kb[c4];
      ((float4*)&Vs[row][0])[c4] = vb[c4];
    }
    __syncthreads();
    float sv[4] = {0.f, 0.f, 0.f, 0.f};
    const float4* qrow = (const float4*)&Qs[r][0];
#pragma unroll 8
    for (int dd = 0; dd < 32; ++dd) {
      int d4 = (dd + (tid & 7) * 4) & 31;
      float4 qv = qrow[d4];
#pragma unroll
      for (int jj = 0; jj < 4; ++jj) {
        float4 kv4 = ((const float4*)&Ks[jb + jj][0])[d4];
        sv[jj] += qv.x * kv4.x + qv.y * kv4.y + qv.z * kv4.z + qv.w * kv4.w;
      }
    }
    int qg = qt * 32 + r;
    float tmax = -1e30f;
#pragma unroll
    for (int jj = 0; jj < 4; ++jj) {
      int jg = jt * 32 + jb + jj;
      sv[jj] = (jg <= qg) ? sv[jj] * scale : -1e30f;
      tmax = fmaxf(tmax, sv[jj]);
    }
#pragma unroll
    for (int msk = 1; msk < 8; msk <<= 1)
      tmax = fmaxf(tmax, __shfl_xor(tmax, msk));
    float mnew = fmaxf(m_run, tmax);
    float f = expf(m_run - mnew);
    float psum = 0.f;
#pragma unroll
    for (int jj = 0; jj < 4; ++jj) {
      float p = expf(sv[jj] - mnew);
      Ss[r][jb + jj] = p;
      psum += p;
    }
#pragma unroll
    for (int msk = 1; msk < 8; msk <<= 1) psum += __shfl_xor(psum, msk);
    l_run = l_run * f + psum;
    m_run = mnew;
#pragma unroll
    for (int i = 0; i < 16; ++i) acc[i] *= f;
    __syncthreads();
#pragma unroll 4
    for (int j = 0; j < 32; ++j) {
      float pj = Ss[r][j];
      const float4* vrow = (const float4*)&Vs[j][0];
#pragma unroll
      for (int dd = 0; dd < 4; ++dd) {
        float4 vv = vrow[(d0 >> 2) + dd];
        acc[dd * 4 + 0] += pj * vv.x;
        acc[dd * 4 + 1] += pj * vv.y;
        acc[dd * 4 + 2] += pj * vv.z;
        acc[dd * 4 + 3] += pj * vv.w;
      }
    }
  }
  float invl = 1.0f / l_run;
  int t = b * S_ + qt * 32 + r;
  size_t obase = (size_t)t * D_ + h * DH_ + d0;
  uint4 h0, h1, l0, l1;
  pack2_split(acc[0] * invl, acc[1] * invl, h0.x, l0.x);
  pack2_split(acc[2] * invl, acc[3] * invl, h0.y, l0.y);
  pack2_split(acc[4] * invl, acc[5] * invl, h0.z, l0.z);
  pack2_split(acc[6] * invl, acc[7] * invl, h0.w, l0.w);
  pack2_split(acc[8] * invl, acc[9] * invl, h1.x, l1.x);
  pack2_split(acc[10] * invl, acc[11] * invl, h1.y, l1.y);
  pack2_split(acc[12] * invl, acc[13] * invl, h1.z, l1.z);
  pack2_split(acc[14] * invl, acc[15] * invl, h1.w, l1.w);
  ((uint4*)(ohi + obase))[0] = h0;
  ((uint4*)(ohi + obase))[1] = h1;
  ((uint4*)(olo + obase))[0] = l0;
  ((uint4*)(olo + obase))[1] = l1;
}

// ---------------- router: fused rmsnorm + logits + softmax top-2 ----------------
__global__ __launch_bounds__(256) void router_k(const float* __restrict__ x2,
                                                const float* __restrict__ lnw,
                                                const float* __restrict__ rw,
                                                float* __restrict__ topv,
                                                int* __restrict__ topi,
                                                int* __restrict__ counts) {
  int t = blockIdx.x;
  int tid = threadIdx.x;
  const float4* row = (const float4*)(x2 + (size_t)t * D_);
  float4 v0 = row[tid * 2], v1 = row[tid * 2 + 1];
  float ss = v0.x*v0.x + v0.y*v0.y + v0.z*v0.z + v0.w*v0.w
           + v1.x*v1.x + v1.y*v1.y + v1.z*v1.z + v1.w*v1.w;
#pragma unroll
  for (int o = 32; o > 0; o >>= 1) ss += __shfl_down(ss, o);
  __shared__ float sred[4];
  if ((tid & 63) == 0) sred[tid >> 6] = ss;
  __syncthreads();
  float tot = sred[0] + sred[1] + sred[2] + sred[3];
  float sc = rsqrtf(tot * (1.0f / D_) + EPS_);
  const float4* w4 = (const float4*)lnw;
  float4 wa = w4[tid * 2], wb = w4[tid * 2 + 1];
  float hv[8] = {v0.x * sc * wa.x, v0.y * sc * wa.y, v0.z * sc * wa.z,
                 v0.w * sc * wa.w, v1.x * sc * wb.x, v1.y * sc * wb.y,
                 v1.z * sc * wb.z, v1.w * sc * wb.w};
  float acc[E_];
#pragma unroll
  for (int e2 = 0; e2 < E_; ++e2) acc[e2] = 0.f;
  int dbase = tid * 8;
#pragma unroll
  for (int jj = 0; jj < 8; ++jj) {
    float xv = hv[jj];
    const float4* rr = (const float4*)(rw + (size_t)(dbase + jj) * E_);
#pragma unroll
    for (int e4 = 0; e4 < 4; ++e4) {
      float4 wv = rr[e4];
      acc[e4 * 4 + 0] += xv * wv.x;
      acc[e4 * 4 + 1] += xv * wv.y;
      acc[e4 * 4 + 2] += xv * wv.z;
      acc[e4 * 4 + 3] += xv * wv.w;
    }
  }
  __shared__ float red[256][E_];
#pragma unroll
  for (int e2 = 0; e2 < E_; ++e2) red[tid][e2] = acc[e2];
  __syncthreads();
  __shared__ float wlog[E_];
  if (tid < E_) {
    float s = 0.f;
    for (int i = 0; i < 256; ++i) s += red[i][tid];
    wlog[tid] = s;
  }
  __syncthreads();
  if (tid == 0) {
    float mx = wlog[0];
    for (int e2 = 1; e2 < E_; ++e2) mx = fmaxf(mx, wlog[e2]);
    float pe[E_];
    float se = 0.f;
    for (int e2 = 0; e2 < E_; ++e2) {
      pe[e2] = expf(wlog[e2] - mx);
      se += pe[e2];
    }
    float invs = 1.f / se;
    for (int e2 = 0; e2 < E_; ++e2) pe[e2] *= invs;
    int i0 = 0;
    float p0 = pe[0];
    for (int e2 = 1; e2 < E_; ++e2)
      if (pe[e2] > p0) { p0 = pe[e2]; i0 = e2; }
    int i1 = -1;
    float p1 = -1.f;
    for (int e2 = 0; e2 < E_; ++e2) {
      if (e2 == i0) continue;
      if (pe[e2] > p1) { p1 = pe[e2]; i1 = e2; }
    }
    float wsum = p0 + p1;
    topi[2 * t] = i0;
    topi[2 * t + 1] = i1;
    topv[2 * t] = p0 / wsum;
    topv[2 * t + 1] = p1 / wsum;
    atomicAdd(&counts[i0], 1);
    atomicAdd(&counts[i1], 1);
  }
}

__global__ void zero_k(int* __restrict__ counts) {
  if (threadIdx.x < E_) counts[threadIdx.x] = 0;
}

__global__ void offsets_k(const int* __restrict__ counts, int* __restrict__ offs,
                          int* __restrict__ cursor) {
  if (threadIdx.x == 0) {
    int s = 0;
    for (int e2 = 0; e2 < E_; ++e2) {
      offs[e2] = s;
      s += counts[e2];
    }
    offs[E_] = s;
  }
  if (threadIdx.x < E_) cursor[threadIdx.x] = 0;
}

__global__ __launch_bounds__(256) void pairs_k(
    const int* __restrict__ topi, const float* __restrict__ topv,
    const int* __restrict__ offs, int* __restrict__ cursor,
    int* __restrict__ pair_token, float* __restrict__ pair_w,
    int* __restrict__ pair_slot) {
  int t = blockIdx.x * blockDim.x + threadIdx.x;
  if (t >= T_) return;
#pragma unroll
  for (int kk = 0; kk < TOPK_; ++kk) {
    int e2 = topi[2 * t + kk];
    int p = offs[e2] + atomicAdd(&cursor[e2], 1);
    pair_token[p] = t;
    pair_w[p] = topv[2 * t + kk];
    pair_slot[p] = 2 * t + kk;
  }
}

// act = silu(g)*u*w -> bf16
__global__ __launch_bounds__(256) void act_k(const float* __restrict__ GU,
                                             const float* __restrict__ pair_w,
                                             ushort* __restrict__ act) {
  int idx = blockIdx.x * blockDim.x + threadIdx.x;
  int stride = gridDim.x * blockDim.x;
  int n4 = T_ * TOPK_ * (I_ / 4);
  const float4* GU4 = (const float4*)GU;
  for (; idx < n4; idx += stride) {
    int p = idx >> 8;
    int i = idx & 255;
    float w = pair_w[p];
    float4 g = GU4[(size_t)p * 512 + i];
    float4 u = GU4[(size_t)p * 512 + 256 + i];
    ushort4 r;
    r.x = f2bf((g.x / (1.f + expf(-g.x))) * u.x * w);
    r.y = f2bf((g.y / (1.f + expf(-g.y))) * u.y * w);
    r.z = f2bf((g.z / (1.f + expf(-g.z))) * u.z * w);
    r.w = f2bf((g.w / (1.f + expf(-g.w))) * u.w * w);
    ((ushort4*)act)[(size_t)p * 256 + i] = r;
  }
}

__global__ __launch_bounds__(256) void final_k(const float* __restrict__ slots,
                                               float* __restrict__ out) {
  int idx = blockIdx.x * blockDim.x + threadIdx.x;
  int stride = gridDim.x * blockDim.x;
  int n4 = T_ * D_ / 4;
  const int rowq = D_ / 4;
  const float4* S4 = (const float4*)slots;
  float4* O4 = (float4*)out;
  for (; idx < n4; idx += stride) {
    int t = idx / rowq;
    int d4 = idx % rowq;
    float4 a = O4[idx];
    float4 s0 = S4[(size_t)(2 * t) * rowq + d4];
    float4 s1 = S4[(size_t)(2 * t + 1) * rowq + d4];
    float4 res;
    res.x = a.x + s0.x + s1.x;
    res.y = a.y + s0.y + s1.y;
    res.z = a.z + s0.z + s1.z;
    res.w = a.w + s0.w + s1.w;
    O4[idx] = res;
  }
}

extern "C" void kernel_launch(void* const* d_in, const int* in_sizes, int n_in,
                              void* d_out, int out_size, void* d_ws, size_t ws_size,
                              hipStream_t stream) {
  const float* x = (const float*)d_in[0];
  const int* pos = (const int*)d_in[1];
  const float* ln1_w = (const float*)d_in[2];
  const float* q_w = (const float*)d_in[3];
  const float* k_w = (const float*)d_in[4];
  const float* v_w = (const float*)d_in[5];
  const float* o_w = (const float*)d_in[6];
  const float* qn_w = (const float*)d_in[7];
  const float* kn_w = (const float*)d_in[8];
  const float* ln2_w = (const float*)d_in[9];
  const float* router_w = (const float*)d_in[10];
  const float* gate_w = (const float*)d_in[11];
  const float* up_w = (const float*)d_in[12];
  const float* down_w = (const float*)d_in[13];
  float* out = (float*)d_out;  // doubles as x2

  char* w = (char*)d_ws;
  ushort* h_hi = (ushort*)w;     w += (size_t)T_ * D_ * 2;  // reused as h2_bf
  ushort* h_lo = (ushort*)w;     w += (size_t)T_ * D_ * 2;
  float* qkv = (float*)w;        w += (size_t)T_ * QKVN_ * 4;
  ushort* o_hi = (ushort*)w;     w += (size_t)T_ * D_ * 2;
  ushort* o_lo = (ushort*)w;     w += (size_t)T_ * D_ * 2;
  ushort* wtq_hi = (ushort*)w;   w += (size_t)QKVN_ * D_ * 2;
  ushort* wtq_lo = (ushort*)w;   w += (size_t)QKVN_ * D_ * 2;
  ushort* wto_hi = (ushort*)w;   w += (size_t)D_ * D_ * 2;
  ushort* wto_lo = (ushort*)w;   w += (size_t)D_ * D_ * 2;
  float* bufGU = (float*)w;      w += (size_t)T_ * TOPK_ * 2048 * 4;
  ushort* act_bf = (ushort*)w;   w += (size_t)T_ * TOPK_ * I_ * 2;
  float* slots = (float*)w;      w += (size_t)T_ * TOPK_ * D_ * 4;
  float* topv = (float*)w;       w += (size_t)T_ * TOPK_ * 4;
  float* pair_w = (float*)w;     w += (size_t)T_ * TOPK_ * 4;
  int* topi = (int*)w;           w += (size_t)T_ * TOPK_ * 4;
  int* counts = (int*)w;         w += 64 * 4;
  int* offs = (int*)w;           w += 64 * 4;
  int* cursor = (int*)w;         w += 64 * 4;
  int* pair_token = (int*)w;     w += (size_t)T_ * TOPK_ * 4;
  int* pair_slot = (int*)w;      w += (size_t)T_ * TOPK_ * 4;
  ushort* h2_bf = h_hi;  // alias: h_hi dead after QKV GEMM

  // weight transposes (split bf16): q,k,v into wtq rows [0,2048,2560); o into wto
  transpose_split_k<<<dim3(64, 64), 256, 0, stream>>>(q_w, wtq_hi, wtq_lo, 2048, 0, D_);
  transpose_split_k<<<dim3(16, 64), 256, 0, stream>>>(k_w, wtq_hi, wtq_lo, 512, 2048, D_);
  transpose_split_k<<<dim3(16, 64), 256, 0, stream>>>(v_w, wtq_hi, wtq_lo, 512, 2560, D_);
  transpose_split_k<<<dim3(64, 64), 256, 0, stream>>>(o_w, wto_hi, wto_lo, 2048, 0, D_);

  // ---- attention block (split-precision path: feeds the router) ----
  rmsnorm_split_k<<<T_, 256, 0, stream>>>(x, ln1_w, h_hi, h_lo);
  gemm_split_k<<<dim3(QKVN_ / 128, T_ / 128), 256, 0, stream>>>(
      h_hi, h_lo, wtq_hi, wtq_lo, qkv, nullptr, T_, QKVN_, D_);
  qknorm_rope_k<<<dim3(T_, H_ + KV_), 128, 0, stream>>>(qkv, qn_w, kn_w, pos);
  attn_k<<<dim3(S_ / 32, B_ * H_), 256, 0, stream>>>(qkv, o_hi, o_lo);
  gemm_split_k<<<dim3(D_ / 128, T_ / 128), 256, 0, stream>>>(
      o_hi, o_lo, wto_hi, wto_lo, out, x, T_, D_, D_);

  // ---- MoE block ----
  zero_k<<<1, 64, 0, stream>>>(counts);
  router_k<<<T_, 256, 0, stream>>>(out, ln2_w, router_w, topv, topi, counts);
  rmsnorm_bf16_k<<<T_, 256, 0, stream>>>(out, ln2_w, h2_bf);
  offsets_k<<<1, 64, 0, stream>>>(counts, offs, cursor);
  pairs_k<<<T_ / 256, 256, 0, stream>>>(topi, topv, offs, cursor, pair_token,
                                        pair_w, pair_slot);
  gemm_k<1><<<dim3(16, 32, E_), 256, 0, stream>>>(
      h2_bf, gate_w, up_w, bufGU, pair_token, nullptr, counts, offs, 2048, D_);
  act_k<<<2048, 256, 0, stream>>>(bufGU, pair_w, act_bf);
  gemm_k<2><<<dim3(16, 32, E_), 256, 0, stream>>>(
      act_bf, down_w, nullptr, slots, nullptr, pair_slot, counts, offs, 2048, I_);
  final_k<<<2048, 256, 0, stream>>>(slots, out);
}

// Round 4
// 649.506 us; speedup vs baseline: 6.8183x; 1.8040x over previous
//
#include <hip/hip_runtime.h>
#include <hip/hip_bf16.h>
#include <math.h>

#define B_ 2
#define S_ 1024
#define T_ (B_*S_)
#define D_ 2048
#define H_ 16
#define KV_ 4
#define DH_ 128
#define E_ 16
#define TOPK_ 2
#define I_ 1024
#define GROUPS_ (H_/KV_)
#define EPS_ 1e-6f
#define QKVN_ 3072

typedef __attribute__((ext_vector_type(8))) short short8;
typedef __attribute__((ext_vector_type(4))) float f32x4;
typedef unsigned int uint;

__device__ __forceinline__ ushort f2bf(float f) {
  union { float f; uint u; } v; v.f = f;
  uint r = v.u + 0x7fffu + ((v.u >> 16) & 1u);
  return (ushort)(r >> 16);
}
__device__ __forceinline__ float bf2f(ushort h) {
  union { uint u; float f; } v; v.u = ((uint)h) << 16;
  return v.f;
}
__device__ __forceinline__ uint pack2(float a, float b) {
  return (uint)f2bf(a) | ((uint)f2bf(b) << 16);
}
__device__ __forceinline__ void split1(float a, ushort& hi, ushort& lo) {
  hi = f2bf(a);
  lo = f2bf(a - bf2f(hi));
}
__device__ __forceinline__ void pack2_split(float a, float b, uint& h, uint& l) {
  ushort ah, al, bh, bl;
  split1(a, ah, al);
  split1(b, bh, bl);
  h = (uint)ah | ((uint)bh << 16);
  l = (uint)al | ((uint)bl << 16);
}
__device__ __forceinline__ void split_f8(const float* t, short8& h8, short8& l8) {
  union { short8 v; ushort u[8]; } H, L;
#pragma unroll
  for (int i = 0; i < 8; ++i) {
    ushort hh, ll;
    split1(t[i], hh, ll);
    H.u[i] = hh; L.u[i] = ll;
  }
  h8 = H.v; l8 = L.v;
}

// ---------------- RMSNorm fp32 -> split bf16 hi/lo ----------------
__global__ __launch_bounds__(256) void rmsnorm_split_k(const float* __restrict__ x,
                                                       const float* __restrict__ w,
                                                       ushort* __restrict__ hi,
                                                       ushort* __restrict__ lo) {
  int t = blockIdx.x;
  int tid = threadIdx.x;
  const float4* row = (const float4*)(x + (size_t)t * D_);
  float4 v0 = row[tid * 2], v1 = row[tid * 2 + 1];
  float ss = v0.x*v0.x + v0.y*v0.y + v0.z*v0.z + v0.w*v0.w
           + v1.x*v1.x + v1.y*v1.y + v1.z*v1.z + v1.w*v1.w;
#pragma unroll
  for (int o = 32; o > 0; o >>= 1) ss += __shfl_down(ss, o);
  __shared__ float sred[4];
  if ((tid & 63) == 0) sred[tid >> 6] = ss;
  __syncthreads();
  float tot = sred[0] + sred[1] + sred[2] + sred[3];
  float sc = rsqrtf(tot * (1.0f / D_) + EPS_);
  const float4* w4 = (const float4*)w;
  float4 wa = w4[tid * 2], wb = w4[tid * 2 + 1];
  uint4 oh, ol;
  pack2_split(v0.x * sc * wa.x, v0.y * sc * wa.y, oh.x, ol.x);
  pack2_split(v0.z * sc * wa.z, v0.w * sc * wa.w, oh.y, ol.y);
  pack2_split(v1.x * sc * wb.x, v1.y * sc * wb.y, oh.z, ol.z);
  pack2_split(v1.z * sc * wb.z, v1.w * sc * wb.w, oh.w, ol.w);
  ((uint4*)(hi + (size_t)t * D_))[tid] = oh;
  ((uint4*)(lo + (size_t)t * D_))[tid] = ol;
}

// ---------------- RMSNorm fp32 -> plain bf16 (expert input) ----------------
__global__ __launch_bounds__(256) void rmsnorm_bf16_k(const float* __restrict__ x,
                                                      const float* __restrict__ w,
                                                      ushort* __restrict__ out) {
  int t = blockIdx.x;
  int tid = threadIdx.x;
  const float4* row = (const float4*)(x + (size_t)t * D_);
  float4 v0 = row[tid * 2], v1 = row[tid * 2 + 1];
  float ss = v0.x*v0.x + v0.y*v0.y + v0.z*v0.z + v0.w*v0.w
           + v1.x*v1.x + v1.y*v1.y + v1.z*v1.z + v1.w*v1.w;
#pragma unroll
  for (int o = 32; o > 0; o >>= 1) ss += __shfl_down(ss, o);
  __shared__ float sred[4];
  if ((tid & 63) == 0) sred[tid >> 6] = ss;
  __syncthreads();
  float tot = sred[0] + sred[1] + sred[2] + sred[3];
  float sc = rsqrtf(tot * (1.0f / D_) + EPS_);
  const float4* w4 = (const float4*)w;
  float4 wa = w4[tid * 2], wb = w4[tid * 2 + 1];
  uint4 o4;
  o4.x = pack2(v0.x * sc * wa.x, v0.y * sc * wa.y);
  o4.y = pack2(v0.z * sc * wa.z, v0.w * sc * wa.w);
  o4.z = pack2(v1.x * sc * wb.x, v1.y * sc * wb.y);
  o4.w = pack2(v1.z * sc * wb.z, v1.w * sc * wb.w);
  ((uint4*)(out + (size_t)t * D_))[tid] = o4;
}

// ---------------- weight transpose + split: W[K][N] -> Wt hi/lo [row_off+n][k] ----------------
__global__ __launch_bounds__(256) void transpose_split_k(
    const float* __restrict__ src, ushort* __restrict__ dhi,
    ushort* __restrict__ dlo, int N, int row_off, int dst_ld) {
  __shared__ float tbuf[32][33];
  int n0 = blockIdx.x * 32, k0 = blockIdx.y * 32;
  int tx = threadIdx.x & 31, ty = threadIdx.x >> 5;
#pragma unroll
  for (int j = 0; j < 4; ++j)
    tbuf[ty + j * 8][tx] = src[(size_t)(k0 + ty + j * 8) * N + n0 + tx];
  __syncthreads();
#pragma unroll
  for (int j = 0; j < 2; ++j) {
    int idx = threadIdx.x + j * 256;
    int n = idx >> 4;
    int kq = (idx & 15) * 2;
    uint ph, pl;
    pack2_split(tbuf[kq][n], tbuf[kq + 1][n], ph, pl);
    size_t o = (size_t)(row_off + n0 + n) * dst_ld + k0 + kq;
    *(uint*)(dhi + o) = ph;
    *(uint*)(dlo + o) = pl;
  }
}

// ---------------- split-bf16 3-pass MFMA GEMM: C = A@B^T (+addend) ----------------
__global__ __launch_bounds__(256) void gemm_split_k(
    const ushort* __restrict__ Ahi, const ushort* __restrict__ Alo,
    const ushort* __restrict__ Bhi, const ushort* __restrict__ Blo,
    float* __restrict__ C, const float* __restrict__ addend,
    int M, int N, int K) {
  int m0 = blockIdx.y * 128, n0 = blockIdx.x * 128;
  __shared__ ushort AsH[128 * 64], AsL[128 * 64];
  __shared__ ushort BsH[128 * 64], BsL[128 * 64];
  int tid = threadIdx.x;
  int row_s = tid >> 1, kh = tid & 1;
  const size_t aoff = (size_t)(m0 + row_s) * K;
  const size_t boff = (size_t)(n0 + row_s) * K;
  int wid = tid >> 6, lane = tid & 63;
  int wr = wid >> 1, wc = wid & 1;
  int lr = lane & 15, lk = lane >> 4;

  f32x4 acc[4][4];
#pragma unroll
  for (int m = 0; m < 4; ++m)
#pragma unroll
    for (int n = 0; n < 4; ++n) acc[m][n] = (f32x4){0.f, 0.f, 0.f, 0.f};

  const int nt = K >> 6;
  for (int t = 0; t < nt; ++t) {
    int k0g = t << 6;
    __syncthreads();
    uint4 r0[4], r1[4], r2[4], r3[4];
#pragma unroll
    for (int c = 0; c < 4; ++c) {
      int k = k0g + kh * 32 + c * 8;
      r0[c] = *(const uint4*)(Ahi + aoff + k);
      r1[c] = *(const uint4*)(Alo + aoff + k);
      r2[c] = *(const uint4*)(Bhi + boff + k);
      r3[c] = *(const uint4*)(Blo + boff + k);
    }
#pragma unroll
    for (int c = 0; c < 4; ++c) {
      int addr = row_s * 128 + (((kh * 4 + c) * 16) ^ ((row_s & 7) << 4));
      *(uint4*)((char*)AsH + addr) = r0[c];
      *(uint4*)((char*)AsL + addr) = r1[c];
      *(uint4*)((char*)BsH + addr) = r2[c];
      *(uint4*)((char*)BsL + addr) = r3[c];
    }
    __syncthreads();
#pragma unroll
    for (int kk = 0; kk < 2; ++kk) {
      short8 ah[4], al[4], bh[4], bl[4];
      int kbyte = kk * 64 + lk * 16;
#pragma unroll
      for (int m = 0; m < 4; ++m) {
        int row = wr * 64 + m * 16 + lr;
        int ad = row * 128 + (kbyte ^ ((row & 7) << 4));
        ah[m] = *(const short8*)((const char*)AsH + ad);
        al[m] = *(const short8*)((const char*)AsL + ad);
      }
#pragma unroll
      for (int n = 0; n < 4; ++n) {
        int row = wc * 64 + n * 16 + lr;
        int ad = row * 128 + (kbyte ^ ((row & 7) << 4));
        bh[n] = *(const short8*)((const char*)BsH + ad);
        bl[n] = *(const short8*)((const char*)BsL + ad);
      }
#pragma unroll
      for (int m = 0; m < 4; ++m)
#pragma unroll
        for (int n = 0; n < 4; ++n) {
          acc[m][n] = __builtin_amdgcn_mfma_f32_16x16x32_bf16(ah[m], bh[n], acc[m][n], 0, 0, 0);
          acc[m][n] = __builtin_amdgcn_mfma_f32_16x16x32_bf16(al[m], bh[n], acc[m][n], 0, 0, 0);
          acc[m][n] = __builtin_amdgcn_mfma_f32_16x16x32_bf16(ah[m], bl[n], acc[m][n], 0, 0, 0);
        }
    }
  }
#pragma unroll
  for (int m = 0; m < 4; ++m) {
    int lrow = wr * 64 + m * 16 + (lane >> 4) * 4;
#pragma unroll
    for (int j = 0; j < 4; ++j) {
      int crow = m0 + lrow + j;
      float* Crow = C + (size_t)crow * N;
#pragma unroll
      for (int n = 0; n < 4; ++n) {
        int col = n0 + wc * 64 + n * 16 + lr;
        float vv = acc[m][n][j];
        if (addend) vv += addend[(size_t)crow * N + col];
        Crow[col] = vv;
      }
    }
  }
}

// ---------------- plain bf16 MFMA GEMM for expert path ----------------
template <int MODE>
__global__ __launch_bounds__(256) void gemm_k(
    const ushort* __restrict__ A, const float* __restrict__ Wf0,
    const float* __restrict__ Wf1, float* __restrict__ C,
    const int* __restrict__ gather, const int* __restrict__ scatter,
    const int* __restrict__ counts, const int* __restrict__ offsets,
    int N, int K) {
  int e = blockIdx.z;
  int cnt = counts[e];
  int m0 = blockIdx.y * 128;
  if (m0 >= cnt) return;
  int off = offsets[e];
  int n0 = blockIdx.x * 128;

  __shared__ ushort As[128 * 64];
  __shared__ ushort Bs[128 * 64];
  __shared__ int rowIdx[128];

  int tid = threadIdx.x;
  if (tid < 128) {
    int lm = m0 + tid;
    rowIdx[tid] = (lm < cnt) ? (gather ? gather[off + lm] : off + lm) : -1;
  }
  __syncthreads();

  const float* Wsel;
  int ldw, nb;
  if (MODE == 1) {
    ldw = 1024;
    Wsel = ((n0 < 1024) ? Wf0 : Wf1) + (size_t)e * (size_t)K * 1024;
    nb = n0 & 1023;
  } else {
    ldw = N;
    Wsel = Wf0 + (size_t)e * (size_t)K * (size_t)N;
    nb = n0;
  }

  const int row_s = tid >> 1;
  const int kh = tid & 1;
  const int arow = rowIdx[row_s];

  uint4 ra[4];
  uint4 rbv[4];
  uint* rb = (uint*)rbv;

  auto loadA = [&](int k0g) {
#pragma unroll
    for (int c = 0; c < 4; ++c) {
      int k = k0g + kh * 32 + c * 8;
      if (arow >= 0)
        ra[c] = *(const uint4*)(A + (size_t)arow * K + k);
      else
        ra[c] = make_uint4(0u, 0u, 0u, 0u);
    }
  };
  auto loadB = [&](int k0g) {
    int col = nb + (tid & 127);
    int kbase = k0g + (tid >> 7) * 32;
    const float* p = Wsel + (size_t)kbase * ldw + col;
#pragma unroll
    for (int i = 0; i < 16; ++i) {
      float f0 = p[(size_t)(2 * i) * ldw];
      float f1 = p[(size_t)(2 * i + 1) * ldw];
      rb[i] = pack2(f0, f1);
    }
  };
  auto writeLDS = [&]() {
    char* Ab = (char*)As;
#pragma unroll
    for (int c = 0; c < 4; ++c) {
      int kbyte = (kh * 4 + c) * 16;
      int addr = row_s * 128 + (kbyte ^ ((row_s & 7) << 4));
      *(uint4*)(Ab + addr) = ra[c];
    }
    char* Bb = (char*)Bs;
    int n_l = tid & 127;
    int khb = tid >> 7;
#pragma unroll
    for (int c = 0; c < 4; ++c) {
      int kbyte = (khb * 4 + c) * 16;
      int addr = n_l * 128 + (kbyte ^ ((n_l & 7) << 4));
      *(uint4*)(Bb + addr) = rbv[c];
    }
  };

  int wid = tid >> 6, lane = tid & 63;
  int wr = wid >> 1, wc = wid & 1;
  int lr = lane & 15, lk = lane >> 4;

  f32x4 acc[4][4];
#pragma unroll
  for (int m = 0; m < 4; ++m)
#pragma unroll
    for (int n = 0; n < 4; ++n) acc[m][n] = (f32x4){0.f, 0.f, 0.f, 0.f};

  const char* Ab = (const char*)As;
  const char* Bb = (const char*)Bs;

  int nt = K >> 6;
  loadA(0);
  loadB(0);
  for (int t = 0; t < nt; ++t) {
    __syncthreads();
    writeLDS();
    __syncthreads();
    if (t + 1 < nt) {
      loadA((t + 1) << 6);
      loadB((t + 1) << 6);
    }
#pragma unroll
    for (int kk = 0; kk < 2; ++kk) {
      short8 af[4], bfv[4];
#pragma unroll
      for (int m = 0; m < 4; ++m) {
        int row = wr * 64 + m * 16 + lr;
        int kbyte = kk * 64 + lk * 16;
        af[m] = *(const short8*)(Ab + row * 128 + (kbyte ^ ((row & 7) << 4)));
      }
#pragma unroll
      for (int n = 0; n < 4; ++n) {
        int row = wc * 64 + n * 16 + lr;
        int kbyte = kk * 64 + lk * 16;
        bfv[n] = *(const short8*)(Bb + row * 128 + (kbyte ^ ((row & 7) << 4)));
      }
#pragma unroll
      for (int m = 0; m < 4; ++m)
#pragma unroll
        for (int n = 0; n < 4; ++n)
          acc[m][n] = __builtin_amdgcn_mfma_f32_16x16x32_bf16(af[m], bfv[n],
                                                              acc[m][n], 0, 0, 0);
    }
  }

#pragma unroll
  for (int m = 0; m < 4; ++m) {
    int lrow = wr * 64 + m * 16 + (lane >> 4) * 4;
#pragma unroll
    for (int j = 0; j < 4; ++j) {
      int lm = lrow + j;
      if (m0 + lm >= cnt) continue;
      int crow;
      if (MODE == 2) crow = scatter[off + m0 + lm];
      else crow = off + m0 + lm;
      float* Crow = C + (size_t)crow * N;
#pragma unroll
      for (int n = 0; n < 4; ++n) {
        int col = n0 + wc * 64 + n * 16 + lr;
        Crow[col] = acc[m][n][j];
      }
    }
  }
}

// ---------------- per-head QK RMSNorm + RoPE on fused qkv (in place) ----------------
__global__ __launch_bounds__(128) void qknorm_rope_k(
    float* __restrict__ qkv, const float* __restrict__ qn_w,
    const float* __restrict__ kn_w, const int* __restrict__ pos_ids) {
  int t = blockIdx.x;
  int head = blockIdx.y;  // 0..15 q, 16..19 k
  int d = threadIdx.x;
  float* base;
  const float* w;
  if (head < H_) {
    base = qkv + (size_t)t * QKVN_ + head * DH_;
    w = qn_w;
  } else {
    base = qkv + (size_t)t * QKVN_ + 2048 + (head - H_) * DH_;
    w = kn_w;
  }
  float val = base[d];
  float ss = val * val;
#pragma unroll
  for (int o = 32; o > 0; o >>= 1) ss += __shfl_down(ss, o);
  __shared__ float sred[2];
  __shared__ float vnorm[DH_];
  if ((d & 63) == 0) sred[d >> 6] = ss;
  __syncthreads();
  float tot = sred[0] + sred[1];
  float sc = rsqrtf(tot * (1.0f / DH_) + EPS_);
  float nv = val * sc * w[d];
  vnorm[d] = nv;
  __syncthreads();
  float pos = (float)pos_ids[t];
  int pi = d & 63;
  float inv = expf(-(2.0f * (float)pi) * (1.0f / 128.0f) * 13.815510558f);
  float ang = pos * inv;
  float c = cosf(ang), s = sinf(ang);
  float partner = (d < 64) ? -vnorm[d + 64] : vnorm[d - 64];
  base[d] = nv * c + partner * s;
}

// ---------------- K split + V transpose-split to global bf16 ----------------
// KgH/KgL: [(b*KV+kvh)][t][d] ; VtH/VtL: [(b*KV+kvh)][d][t]
__global__ __launch_bounds__(256) void kv_prep_k(
    const float* __restrict__ qkv, ushort* __restrict__ KgH,
    ushort* __restrict__ KgL, ushort* __restrict__ VtH,
    ushort* __restrict__ VtL) {
  int tt = blockIdx.x;          // 64-row t tile
  int bk = blockIdx.y;          // b*KV + kvh
  int b = bk >> 2, kvh = bk & 3;
  int tid = threadIdx.x;
  __shared__ float vb[64][129];
#pragma unroll
  for (int i = 0; i < 8; ++i) {
    int idx = tid + i * 256;            // float4 index over 64x32
    int t = idx >> 5, dq = idx & 31;    // dq = d/4
    size_t gt = (size_t)(b * S_ + tt * 64 + t) * QKVN_ + 2048 + kvh * DH_ + dq * 4;
    float4 kk = *(const float4*)(qkv + gt);
    float4 vv = *(const float4*)(qkv + gt + 512);
    ushort4 khv, klv;
    split1(kk.x, khv.x, klv.x);
    split1(kk.y, khv.y, klv.y);
    split1(kk.z, khv.z, klv.z);
    split1(kk.w, khv.w, klv.w);
    size_t go = ((size_t)bk * S_ + tt * 64 + t) * DH_ + dq * 4;
    *(ushort4*)(KgH + go) = khv;
    *(ushort4*)(KgL + go) = klv;
    vb[t][dq * 4 + 0] = vv.x;
    vb[t][dq * 4 + 1] = vv.y;
    vb[t][dq * 4 + 2] = vv.z;
    vb[t][dq * 4 + 3] = vv.w;
  }
  __syncthreads();
  // write V^T rows: thread -> (d = tid>>1, half = tid&1) covers 32 t values
  int d = tid >> 1, half = tid & 1;
  ushort th[32], tl[32];
#pragma unroll
  for (int i = 0; i < 32; ++i) {
    split1(vb[half * 32 + i][d], th[i], tl[i]);
  }
  size_t vo = ((size_t)bk * DH_ + d) * S_ + tt * 64 + half * 32;
#pragma unroll
  for (int i = 0; i < 4; ++i) {
    *(uint4*)(VtH + vo + i * 8) = ((uint4*)th)[i];
    *(uint4*)(VtL + vo + i * 8) = ((uint4*)tl)[i];
  }
}

// ---------------- MFMA flash attention (split bf16, 3-pass) ----------------
__global__ __launch_bounds__(256) void attn_mfma_k(
    const float* __restrict__ qkv,
    const ushort* __restrict__ KgH, const ushort* __restrict__ KgL,
    const ushort* __restrict__ VtH, const ushort* __restrict__ VtL,
    ushort* __restrict__ ohi, ushort* __restrict__ olo) {
  const int qt = blockIdx.x;       // 64 q rows
  const int bh = blockIdx.y;
  const int b = bh >> 4, h = bh & 15;
  const int bk = b * KV_ + (h >> 2);
  const int tid = threadIdx.x;
  const int wid = tid >> 6, lane = tid & 63;
  const int lr = lane & 15, lk = lane >> 4;

  __shared__ ushort KsH[64 * 128], KsL[64 * 128];   // [kt][d] swizzled, 16KB each
  __shared__ ushort VsH[128 * 64], VsL[128 * 64];   // [d][kt] swizzled, 16KB each
  __shared__ float Ps[4][16 * 64];                  // per-wave P fp32, swizzled

  // ---- Q fragments (A-layout): row=lr, k chunks of 8 at lk*8 ----
  short8 qh[4], ql[4];
  {
    int qrow = b * S_ + qt * 64 + wid * 16 + lr;
    const float* qp = qkv + (size_t)qrow * QKVN_ + h * DH_;
#pragma unroll
    for (int c = 0; c < 4; ++c) {
      float tv[8];
      const float* p = qp + c * 32 + lk * 8;
#pragma unroll
      for (int i = 0; i < 8; ++i) tv[i] = p[i];
      split_f8(tv, qh[c], ql[c]);
    }
  }

  f32x4 oacc[8];
#pragma unroll
  for (int n = 0; n < 8; ++n) oacc[n] = (f32x4){0.f, 0.f, 0.f, 0.f};
  float m_run[4] = {-1e30f, -1e30f, -1e30f, -1e30f};
  float l_run[4] = {0.f, 0.f, 0.f, 0.f};
  const float scale2 = 0.12751649736230818f;  // (1/sqrt(128)) * log2(e)

  for (int jt = 0; jt <= qt; ++jt) {
    __syncthreads();
    // ---- stage K tile [64][128] and V^T tile [128][64], hi/lo, swizzled ----
#pragma unroll
    for (int i = 0; i < 4; ++i) {
      int idx = tid + i * 256;
      int kt = idx >> 4, dq = idx & 15;
      size_t g = ((size_t)bk * S_ + jt * 64 + kt) * DH_ + dq * 8;
      uint4 vh = *(const uint4*)(KgH + g);
      uint4 vl = *(const uint4*)(KgL + g);
      int ad = kt * 256 + ((dq * 16) ^ ((kt & 7) << 4));
      *(uint4*)((char*)KsH + ad) = vh;
      *(uint4*)((char*)KsL + ad) = vl;
    }
#pragma unroll
    for (int i = 0; i < 4; ++i) {
      int idx = tid + i * 256;
      int d = idx >> 3, tq = idx & 7;
      size_t g = ((size_t)bk * DH_ + d) * S_ + jt * 64 + tq * 8;
      uint4 vh = *(const uint4*)(VtH + g);
      uint4 vl = *(const uint4*)(VtL + g);
      int ad = d * 128 + ((tq * 16) ^ ((d & 7) << 4));
      *(uint4*)((char*)VsH + ad) = vh;
      *(uint4*)((char*)VsL + ad) = vl;
    }
    __syncthreads();

    // ---- QK^T: S[16 q][64 kt] per wave, 3-pass split ----
    f32x4 sacc[4];
#pragma unroll
    for (int n = 0; n < 4; ++n) sacc[n] = (f32x4){0.f, 0.f, 0.f, 0.f};
#pragma unroll
    for (int n = 0; n < 4; ++n) {
      int row = n * 16 + lr;
      int sw = (row & 7) << 4;
#pragma unroll
      for (int c = 0; c < 4; ++c) {
        int ad = row * 256 + ((c * 64 + lk * 16) ^ sw);
        short8 kh8 = *(const short8*)((const char*)KsH + ad);
        short8 kl8 = *(const short8*)((const char*)KsL + ad);
        sacc[n] = __builtin_amdgcn_mfma_f32_16x16x32_bf16(qh[c], kh8, sacc[n], 0, 0, 0);
        sacc[n] = __builtin_amdgcn_mfma_f32_16x16x32_bf16(ql[c], kh8, sacc[n], 0, 0, 0);
        sacc[n] = __builtin_amdgcn_mfma_f32_16x16x32_bf16(qh[c], kl8, sacc[n], 0, 0, 0);
      }
    }

    // ---- online softmax (exp2 domain). D rows: q = lk*4+j ----
    float p[4][4];
    float mnew[4], f[4], psum[4];
#pragma unroll
    for (int j = 0; j < 4; ++j) {
      int qg = qt * 64 + wid * 16 + lk * 4 + j;
      float mx = -1e30f;
#pragma unroll
      for (int n = 0; n < 4; ++n) {
        int ktg = jt * 64 + n * 16 + lr;
        float s = (ktg <= qg) ? sacc[n][j] * scale2 : -1e30f;
        p[n][j] = s;
        mx = fmaxf(mx, s);
      }
#pragma unroll
      for (int msk = 1; msk < 16; msk <<= 1)
        mx = fmaxf(mx, __shfl_xor(mx, msk));
      mnew[j] = fmaxf(m_run[j], mx);
      f[j] = exp2f(m_run[j] - mnew[j]);
      float ps = 0.f;
#pragma unroll
      for (int n = 0; n < 4; ++n) {
        float pv = exp2f(p[n][j] - mnew[j]);
        p[n][j] = pv;
        ps += pv;
      }
      psum[j] = ps;
    }
#pragma unroll
    for (int j = 0; j < 4; ++j) {
#pragma unroll
      for (int msk = 1; msk < 16; msk <<= 1) psum[j] += __shfl_xor(psum[j], msk);
      l_run[j] = l_run[j] * f[j] + psum[j];
      m_run[j] = mnew[j];
    }
#pragma unroll
    for (int n = 0; n < 8; ++n) {
      f32x4 o = oacc[n];
      o[0] *= f[0]; o[1] *= f[1]; o[2] *= f[2]; o[3] *= f[3];
      oacc[n] = o;
    }

    // ---- write P to per-wave LDS (fp32, swizzled rows of 256B) ----
    {
      char* Pw = (char*)&Ps[wid][0];
#pragma unroll
      for (int j = 0; j < 4; ++j) {
        int q = lk * 4 + j;
        int sw = (q & 7) << 5;
#pragma unroll
        for (int n = 0; n < 4; ++n) {
          int kt2 = n * 16 + lr;
          *(float*)(Pw + q * 256 + ((kt2 * 4) ^ sw)) = p[n][j];
        }
      }
    }

    // ---- PV: O[16 q][128 d] += P @ V^T, 3-pass split ----
    {
      const char* Pw = (const char*)&Ps[wid][0];
      int swp = (lr & 7) << 5;
#pragma unroll
      for (int c2 = 0; c2 < 2; ++c2) {
        int base = lr * 256 + ((c2 * 128 + lk * 32) ^ swp);
        float tv[8];
        *(float4*)&tv[0] = *(const float4*)(Pw + base);
        *(float4*)&tv[4] = *(const float4*)(Pw + base + 16);
        short8 ph, pl;
        split_f8(tv, ph, pl);
#pragma unroll
        for (int n = 0; n < 8; ++n) {
          int row = n * 16 + lr;
          int ad = row * 128 + ((c2 * 64 + lk * 16) ^ ((row & 7) << 4));
          short8 vh8 = *(const short8*)((const char*)VsH + ad);
          short8 vl8 = *(const short8*)((const char*)VsL + ad);
          oacc[n] = __builtin_amdgcn_mfma_f32_16x16x32_bf16(ph, vh8, oacc[n], 0, 0, 0);
          oacc[n] = __builtin_amdgcn_mfma_f32_16x16x32_bf16(pl, vh8, oacc[n], 0, 0, 0);
          oacc[n] = __builtin_amdgcn_mfma_f32_16x16x32_bf16(ph, vl8, oacc[n], 0, 0, 0);
        }
      }
    }
  }

  // ---- epilogue: normalize + split-store ----
  float invl[4];
#pragma unroll
  for (int j = 0; j < 4; ++j) invl[j] = 1.0f / l_run[j];
#pragma unroll
  for (int j = 0; j < 4; ++j) {
    int t = b * S_ + qt * 64 + wid * 16 + lk * 4 + j;
    size_t ob = (size_t)t * D_ + h * DH_ + lr;
#pragma unroll
    for (int n = 0; n < 8; ++n) {
      float val = oacc[n][j] * invl[j];
      ushort vh, vl;
      split1(val, vh, vl);
      ohi[ob + n * 16] = vh;
      olo[ob + n * 16] = vl;
    }
  }
}

// ---------------- router: fused rmsnorm + logits + softmax top-2 ----------------
__global__ __launch_bounds__(256) void router_k(const float* __restrict__ x2,
                                                const float* __restrict__ lnw,
                                                const float* __restrict__ rw,
                                                float* __restrict__ topv,
                                                int* __restrict__ topi,
                                                int* __restrict__ counts) {
  int t = blockIdx.x;
  int tid = threadIdx.x;
  const float4* row = (const float4*)(x2 + (size_t)t * D_);
  float4 v0 = row[tid * 2], v1 = row[tid * 2 + 1];
  float ss = v0.x*v0.x + v0.y*v0.y + v0.z*v0.z + v0.w*v0.w
           + v1.x*v1.x + v1.y*v1.y + v1.z*v1.z + v1.w*v1.w;
#pragma unroll
  for (int o = 32; o > 0; o >>= 1) ss += __shfl_down(ss, o);
  __shared__ float sred[4];
  if ((tid & 63) == 0) sred[tid >> 6] = ss;
  __syncthreads();
  float tot = sred[0] + sred[1] + sred[2] + sred[3];
  float sc = rsqrtf(tot * (1.0f / D_) + EPS_);
  const float4* w4 = (const float4*)lnw;
  float4 wa = w4[tid * 2], wb = w4[tid * 2 + 1];
  float hv[8] = {v0.x * sc * wa.x, v0.y * sc * wa.y, v0.z * sc * wa.z,
                 v0.w * sc * wa.w, v1.x * sc * wb.x, v1.y * sc * wb.y,
                 v1.z * sc * wb.z, v1.w * sc * wb.w};
  float acc[E_];
#pragma unroll
  for (int e2 = 0; e2 < E_; ++e2) acc[e2] = 0.f;
  int dbase = tid * 8;
#pragma unroll
  for (int jj = 0; jj < 8; ++jj) {
    float xv = hv[jj];
    const float4* rr = (const float4*)(rw + (size_t)(dbase + jj) * E_);
#pragma unroll
    for (int e4 = 0; e4 < 4; ++e4) {
      float4 wv = rr[e4];
      acc[e4 * 4 + 0] += xv * wv.x;
      acc[e4 * 4 + 1] += xv * wv.y;
      acc[e4 * 4 + 2] += xv * wv.z;
      acc[e4 * 4 + 3] += xv * wv.w;
    }
  }
  __shared__ float red[256][E_];
#pragma unroll
  for (int e2 = 0; e2 < E_; ++e2) red[tid][e2] = acc[e2];
  __syncthreads();
  __shared__ float wlog[E_];
  if (tid < E_) {
    float s = 0.f;
    for (int i = 0; i < 256; ++i) s += red[i][tid];
    wlog[tid] = s;
  }
  __syncthreads();
  if (tid == 0) {
    float mx = wlog[0];
    for (int e2 = 1; e2 < E_; ++e2) mx = fmaxf(mx, wlog[e2]);
    float pe[E_];
    float se = 0.f;
    for (int e2 = 0; e2 < E_; ++e2) {
      pe[e2] = expf(wlog[e2] - mx);
      se += pe[e2];
    }
    float invs = 1.f / se;
    for (int e2 = 0; e2 < E_; ++e2) pe[e2] *= invs;
    int i0 = 0;
    float p0 = pe[0];
    for (int e2 = 1; e2 < E_; ++e2)
      if (pe[e2] > p0) { p0 = pe[e2]; i0 = e2; }
    int i1 = -1;
    float p1 = -1.f;
    for (int e2 = 0; e2 < E_; ++e2) {
      if (e2 == i0) continue;
      if (pe[e2] > p1) { p1 = pe[e2]; i1 = e2; }
    }
    float wsum = p0 + p1;
    topi[2 * t] = i0;
    topi[2 * t + 1] = i1;
    topv[2 * t] = p0 / wsum;
    topv[2 * t + 1] = p1 / wsum;
    atomicAdd(&counts[i0], 1);
    atomicAdd(&counts[i1], 1);
  }
}

__global__ void zero_k(int* __restrict__ counts) {
  if (threadIdx.x < E_) counts[threadIdx.x] = 0;
}

__global__ void offsets_k(const int* __restrict__ counts, int* __restrict__ offs,
                          int* __restrict__ cursor) {
  if (threadIdx.x == 0) {
    int s = 0;
    for (int e2 = 0; e2 < E_; ++e2) {
      offs[e2] = s;
      s += counts[e2];
    }
    offs[E_] = s;
  }
  if (threadIdx.x < E_) cursor[threadIdx.x] = 0;
}

__global__ __launch_bounds__(256) void pairs_k(
    const int* __restrict__ topi, const float* __restrict__ topv,
    const int* __restrict__ offs, int* __restrict__ cursor,
    int* __restrict__ pair_token, float* __restrict__ pair_w,
    int* __restrict__ pair_slot) {
  int t = blockIdx.x * blockDim.x + threadIdx.x;
  if (t >= T_) return;
#pragma unroll
  for (int kk = 0; kk < TOPK_; ++kk) {
    int e2 = topi[2 * t + kk];
    int p = offs[e2] + atomicAdd(&cursor[e2], 1);
    pair_token[p] = t;
    pair_w[p] = topv[2 * t + kk];
    pair_slot[p] = 2 * t + kk;
  }
}

// act = silu(g)*u*w -> bf16
__global__ __launch_bounds__(256) void act_k(const float* __restrict__ GU,
                                             const float* __restrict__ pair_w,
                                             ushort* __restrict__ act) {
  int idx = blockIdx.x * blockDim.x + threadIdx.x;
  int stride = gridDim.x * blockDim.x;
  int n4 = T_ * TOPK_ * (I_ / 4);
  const float4* GU4 = (const float4*)GU;
  for (; idx < n4; idx += stride) {
    int p = idx >> 8;
    int i = idx & 255;
    float w = pair_w[p];
    float4 g = GU4[(size_t)p * 512 + i];
    float4 u = GU4[(size_t)p * 512 + 256 + i];
    ushort4 r;
    r.x = f2bf((g.x / (1.f + expf(-g.x))) * u.x * w);
    r.y = f2bf((g.y / (1.f + expf(-g.y))) * u.y * w);
    r.z = f2bf((g.z / (1.f + expf(-g.z))) * u.z * w);
    r.w = f2bf((g.w / (1.f + expf(-g.w))) * u.w * w);
    ((ushort4*)act)[(size_t)p * 256 + i] = r;
  }
}

__global__ __launch_bounds__(256) void final_k(const float* __restrict__ slots,
                                               float* __restrict__ out) {
  int idx = blockIdx.x * blockDim.x + threadIdx.x;
  int stride = gridDim.x * blockDim.x;
  int n4 = T_ * D_ / 4;
  const int rowq = D_ / 4;
  const float4* S4 = (const float4*)slots;
  float4* O4 = (float4*)out;
  for (; idx < n4; idx += stride) {
    int t = idx / rowq;
    int d4 = idx % rowq;
    float4 a = O4[idx];
    float4 s0 = S4[(size_t)(2 * t) * rowq + d4];
    float4 s1 = S4[(size_t)(2 * t + 1) * rowq + d4];
    float4 res;
    res.x = a.x + s0.x + s1.x;
    res.y = a.y + s0.y + s1.y;
    res.z = a.z + s0.z + s1.z;
    res.w = a.w + s0.w + s1.w;
    O4[idx] = res;
  }
}

extern "C" void kernel_launch(void* const* d_in, const int* in_sizes, int n_in,
                              void* d_out, int out_size, void* d_ws, size_t ws_size,
                              hipStream_t stream) {
  const float* x = (const float*)d_in[0];
  const int* pos = (const int*)d_in[1];
  const float* ln1_w = (const float*)d_in[2];
  const float* q_w = (const float*)d_in[3];
  const float* k_w = (const float*)d_in[4];
  const float* v_w = (const float*)d_in[5];
  const float* o_w = (const float*)d_in[6];
  const float* qn_w = (const float*)d_in[7];
  const float* kn_w = (const float*)d_in[8];
  const float* ln2_w = (const float*)d_in[9];
  const float* router_w = (const float*)d_in[10];
  const float* gate_w = (const float*)d_in[11];
  const float* up_w = (const float*)d_in[12];
  const float* down_w = (const float*)d_in[13];
  float* out = (float*)d_out;  // doubles as x2

  char* w = (char*)d_ws;
  ushort* h_hi = (ushort*)w;     w += (size_t)T_ * D_ * 2;  // reused as h2_bf
  ushort* h_lo = (ushort*)w;     w += (size_t)T_ * D_ * 2;
  float* qkv = (float*)w;        w += (size_t)T_ * QKVN_ * 4;
  ushort* o_hi = (ushort*)w;     w += (size_t)T_ * D_ * 2;
  ushort* o_lo = (ushort*)w;     w += (size_t)T_ * D_ * 2;
  ushort* wtq_hi = (ushort*)w;   w += (size_t)QKVN_ * D_ * 2;
  ushort* wtq_lo = (ushort*)w;   w += (size_t)QKVN_ * D_ * 2;
  ushort* wto_hi = (ushort*)w;   w += (size_t)D_ * D_ * 2;
  ushort* wto_lo = (ushort*)w;   w += (size_t)D_ * D_ * 2;
  ushort* KgH = (ushort*)w;      w += (size_t)B_ * KV_ * S_ * DH_ * 2;
  ushort* KgL = (ushort*)w;      w += (size_t)B_ * KV_ * S_ * DH_ * 2;
  ushort* VtH = (ushort*)w;      w += (size_t)B_ * KV_ * S_ * DH_ * 2;
  ushort* VtL = (ushort*)w;      w += (size_t)B_ * KV_ * S_ * DH_ * 2;
  float* bufGU = (float*)w;      w += (size_t)T_ * TOPK_ * 2048 * 4;
  ushort* act_bf = (ushort*)w;   w += (size_t)T_ * TOPK_ * I_ * 2;
  float* slots = (float*)w;      w += (size_t)T_ * TOPK_ * D_ * 4;
  float* topv = (float*)w;       w += (size_t)T_ * TOPK_ * 4;
  float* pair_w = (float*)w;     w += (size_t)T_ * TOPK_ * 4;
  int* topi = (int*)w;           w += (size_t)T_ * TOPK_ * 4;
  int* counts = (int*)w;         w += 64 * 4;
  int* offs = (int*)w;           w += 64 * 4;
  int* cursor = (int*)w;         w += 64 * 4;
  int* pair_token = (int*)w;     w += (size_t)T_ * TOPK_ * 4;
  int* pair_slot = (int*)w;      w += (size_t)T_ * TOPK_ * 4;
  ushort* h2_bf = h_hi;  // alias: h_hi dead after QKV GEMM

  // weight transposes (split bf16)
  transpose_split_k<<<dim3(64, 64), 256, 0, stream>>>(q_w, wtq_hi, wtq_lo, 2048, 0, D_);
  transpose_split_k<<<dim3(16, 64), 256, 0, stream>>>(k_w, wtq_hi, wtq_lo, 512, 2048, D_);
  transpose_split_k<<<dim3(16, 64), 256, 0, stream>>>(v_w, wtq_hi, wtq_lo, 512, 2560, D_);
  transpose_split_k<<<dim3(64, 64), 256, 0, stream>>>(o_w, wto_hi, wto_lo, 2048, 0, D_);

  // ---- attention block (split-precision path: feeds the router) ----
  rmsnorm_split_k<<<T_, 256, 0, stream>>>(x, ln1_w, h_hi, h_lo);
  gemm_split_k<<<dim3(QKVN_ / 128, T_ / 128), 256, 0, stream>>>(
      h_hi, h_lo, wtq_hi, wtq_lo, qkv, nullptr, T_, QKVN_, D_);
  qknorm_rope_k<<<dim3(T_, H_ + KV_), 128, 0, stream>>>(qkv, qn_w, kn_w, pos);
  kv_prep_k<<<dim3(S_ / 64, B_ * KV_), 256, 0, stream>>>(qkv, KgH, KgL, VtH, VtL);
  attn_mfma_k<<<dim3(S_ / 64, B_ * H_), 256, 0, stream>>>(
      qkv, KgH, KgL, VtH, VtL, o_hi, o_lo);
  gemm_split_k<<<dim3(D_ / 128, T_ / 128), 256, 0, stream>>>(
      o_hi, o_lo, wto_hi, wto_lo, out, x, T_, D_, D_);

  // ---- MoE block ----
  zero_k<<<1, 64, 0, stream>>>(counts);
  router_k<<<T_, 256, 0, stream>>>(out, ln2_w, router_w, topv, topi, counts);
  rmsnorm_bf16_k<<<T_, 256, 0, stream>>>(out, ln2_w, h2_bf);
  offsets_k<<<1, 64, 0, stream>>>(counts, offs, cursor);
  pairs_k<<<T_ / 256, 256, 0, stream>>>(topi, topv, offs, cursor, pair_token,
                                        pair_w, pair_slot);
  gemm_k<1><<<dim3(16, 32, E_), 256, 0, stream>>>(
      h2_bf, gate_w, up_w, bufGU, pair_token, nullptr, counts, offs, 2048, D_);
  act_k<<<2048, 256, 0, stream>>>(bufGU, pair_w, act_bf);
  gemm_k<2><<<dim3(16, 32, E_), 256, 0, stream>>>(
      act_bf, down_w, nullptr, slots, nullptr, pair_slot, counts, offs, 2048, I_);
  final_k<<<2048, 256, 0, stream>>>(slots, out);
}